// Round 1
// 322.227 us; speedup vs baseline: 1.0235x; 1.0235x over previous
//
#include <hip/hip_runtime.h>
#include <math.h>

#define EPS 1e-8f
#define NB_SORT 256  // blocks in coarse sort phases

#if defined(__has_builtin)
#if __has_builtin(__builtin_amdgcn_sdot4)
#define HAVE_SDOT4 1
#endif
#endif

typedef __attribute__((ext_vector_type(8))) short bf16x8;
typedef __attribute__((ext_vector_type(4))) float f32x4;

__device__ __forceinline__ int sdot4i(int a, int b, int c) {
#ifdef HAVE_SDOT4
  return __builtin_amdgcn_sdot4(a, b, c, false);
#else
  return c + ((int)(signed char)(a)) * ((int)(signed char)(b)) +
         ((int)(signed char)(a >> 8)) * ((int)(signed char)(b >> 8)) +
         ((int)(signed char)(a >> 16)) * ((int)(signed char)(b >> 16)) +
         (a >> 24) * (b >> 24);
#endif
}

__device__ __forceinline__ float wave_reduce_sum(float v) {
#pragma unroll
  for (int off = 32; off > 0; off >>= 1)
    v += __shfl_xor(v, off, 64);
  return v;
}

__device__ __forceinline__ float wave_reduce_max(float v) {
#pragma unroll
  for (int off = 32; off > 0; off >>= 1)
    v = fmaxf(v, __shfl_xor(v, off, 64));
  return v;
}

__device__ __forceinline__ float dot4(float4 a, float4 b) {
  return a.x * b.x + a.y * b.y + a.z * b.z + a.w * b.w;
}

__device__ __forceinline__ int clampq(float q) {
  int i = (int)rintf(q);
  return i < -127 ? -127 : (i > 127 ? 127 : i);
}

// split fp32 into bf16 hi (truncate) + bf16 lo (exact residual, truncate)
// |x - (hi+lo)| <= 2^-16 |x|  (residual x-hi is exactly representable)
__device__ __forceinline__ void split_bf16(float x, unsigned int& hi,
                                           unsigned int& lo) {
  unsigned int u = __float_as_uint(x);
  hi = u >> 16;
  float hf = __uint_as_float(u & 0xFFFF0000u);
  float r = x - hf;
  lo = __float_as_uint(r) >> 16;
}

// ============ CSR build: 2-level bucket sort, LDS atomics only ============
__global__ __launch_bounds__(256) void hist_coarse(const int* __restrict__ dst,
                                                   int* __restrict__ hist_blk,
                                                   int E, int nbuck) {
  __shared__ int lh[1024];
  int t = threadIdx.x, blk = blockIdx.x;
  for (int i = t; i < nbuck; i += 256) lh[i] = 0;
  __syncthreads();
  int ch = (E + NB_SORT - 1) / NB_SORT;
  int lo = blk * ch, hi = min(E, lo + ch);
  for (int e = lo + t; e < hi; e += 256) atomicAdd(&lh[dst[e] >> 6], 1);
  __syncthreads();
  for (int i = t; i < nbuck; i += 256) hist_blk[i * NB_SORT + blk] = lh[i];
}

__global__ __launch_bounds__(256) void scan_local(int* __restrict__ hist,
                                                  int* __restrict__ bsum,
                                                  int nb) {
  __shared__ int tsum[256];
  int t = threadIdx.x;
  int base = blockIdx.x * 1024 + t * 4;
  int v0 = 0, v1 = 0, v2 = 0, v3 = 0;
  if (base + 3 < nb) {
    int4 q = *(const int4*)&hist[base];
    v0 = q.x; v1 = q.y; v2 = q.z; v3 = q.w;
  } else {
    if (base + 0 < nb) v0 = hist[base + 0];
    if (base + 1 < nb) v1 = hist[base + 1];
    if (base + 2 < nb) v2 = hist[base + 2];
  }
  tsum[t] = v0 + v1 + v2 + v3;
  __syncthreads();
  for (int off = 1; off < 256; off <<= 1) {
    int u = 0;
    if (t >= off) u = tsum[t - off];
    __syncthreads();
    if (t >= off) tsum[t] += u;
    __syncthreads();
  }
  int excl = (t == 0) ? 0 : tsum[t - 1];
  int e0 = excl, e1 = excl + v0, e2 = e1 + v1, e3 = e2 + v2;
  if (base + 3 < nb) {
    *(int4*)&hist[base] = make_int4(e0, e1, e2, e3);
  } else {
    if (base + 0 < nb) hist[base + 0] = e0;
    if (base + 1 < nb) hist[base + 1] = e1;
    if (base + 2 < nb) hist[base + 2] = e2;
  }
  if (t == 255) bsum[blockIdx.x] = tsum[255];
}

__global__ __launch_bounds__(256) void scan_bsum(int* __restrict__ bsum,
                                                 int nblk) {
  __shared__ int sh[256];
  int t = threadIdx.x;
  sh[t] = (t < nblk) ? bsum[t] : 0;
  __syncthreads();
  for (int off = 1; off < 256; off <<= 1) {
    int u = 0;
    if (t >= off) u = sh[t - off];
    __syncthreads();
    if (t >= off) sh[t] += u;
    __syncthreads();
  }
  if (t < nblk) bsum[t] = (t == 0) ? 0 : sh[t - 1];
}

__global__ __launch_bounds__(256) void add_bsum(int* __restrict__ hist,
                                                const int* __restrict__ bsum,
                                                int nb) {
  int i = blockIdx.x * blockDim.x + threadIdx.x;
  if (i < nb) hist[i] += bsum[i >> 10];
}

__global__ __launch_bounds__(256) void scatter_coarse(
    const int* __restrict__ src, const int* __restrict__ dst,
    const int* __restrict__ S, int2* __restrict__ epair, int E, int nbuck) {
  __shared__ int lb[1024];
  int t = threadIdx.x, blk = blockIdx.x;
  for (int i = t; i < nbuck; i += 256) lb[i] = S[i * NB_SORT + blk];
  __syncthreads();
  int ch = (E + NB_SORT - 1) / NB_SORT;
  int lo = blk * ch, hi = min(E, lo + ch);
  for (int e = lo + t; e < hi; e += 256) {
    int d = dst[e];
    int pos = atomicAdd(&lb[d >> 6], 1);
    epair[pos] = make_int2(src[e], d);
  }
}

__global__ __launch_bounds__(256) void fine_sort(
    const int2* __restrict__ epair, const int* __restrict__ S,
    int* __restrict__ ssrc, int* __restrict__ endoff, int E, int nbuck,
    int N) {
  __shared__ int fh[64];
  __shared__ int cur[64];
  int b = blockIdx.x, t = threadIdx.x;
  int bstart = S[b * NB_SORT];
  int bend = (b + 1 < nbuck) ? S[(b + 1) * NB_SORT] : E;
  if (t < 64) fh[t] = 0;
  __syncthreads();
  for (int e = bstart + t; e < bend; e += 256)
    atomicAdd(&fh[epair[e].y & 63], 1);
  __syncthreads();
  if (t < 64) {
    int v = fh[t];
    int incl = v;
#pragma unroll
    for (int off = 1; off < 64; off <<= 1) {
      int u = __shfl_up(incl, off, 64);
      if (t >= off) incl += u;
    }
    cur[t] = incl - v;
    int d = b * 64 + t;
    if (d < N) endoff[d] = bstart + incl;
  }
  __syncthreads();
  for (int e = bstart + t; e < bend; e += 256) {
    int2 p = epair[e];
    int pos = atomicAdd(&cur[p.y & 63], 1);
    ssrc[bstart + pos] = p.x;
  }
}

// ============ prep: quantize + node props + self-loop agg init ============
__global__ __launch_bounds__(256) void prep_x(const float* __restrict__ x,
                                              signed char* __restrict__ qx,
                                              float4* __restrict__ nprop,
                                              float* __restrict__ agg,
                                              int N) {
  int node = (int)((blockIdx.x * blockDim.x + threadIdx.x) >> 6);
  int lane = threadIdx.x & 63;
  if (node >= N) return;
  float2 v = *(const float2*)(x + (size_t)node * 128 + lane * 2);
  float ax = fabsf(v.x), ay = fabsf(v.y);
  float mx = wave_reduce_max(fmaxf(ax, ay));
  float l1 = wave_reduce_sum(ax + ay);
  float ss = wave_reduce_sum(v.x * v.x + v.y * v.y);
  float s = mx * (1.0f / 127.0f);
  float inv = (mx > 0.f) ? 127.0f / mx : 0.f;
  int q0 = clampq(v.x * inv), q1 = clampq(v.y * inv);
  unsigned short w = (unsigned short)((q0 & 0xff) | ((q1 & 0xff) << 8));
  ((unsigned short*)(qx + (size_t)node * 128))[lane] = w;
  float l1q = s * wave_reduce_sum((float)(abs(q0) + abs(q1)));
  bool sp = ss > 0.5f * fmaxf(ss, EPS);
  *(float2*)(agg + (size_t)node * 128 + lane * 2) =
      sp ? v : make_float2(0.f, 0.f);
  if (lane == 0)
    nprop[node] = make_float4(sqrtf(ss), s, fmaxf(l1, l1q), 0.f);
}

__global__ __launch_bounds__(256) void prep_h(const float* __restrict__ h,
                                              signed char* __restrict__ qh,
                                              float4* __restrict__ nprop,
                                              float* __restrict__ agg,
                                              int N) {
  int node = (int)((blockIdx.x * blockDim.x + threadIdx.x) >> 6);
  int lane = threadIdx.x & 63;
  if (node >= N) return;
  float4 v = *(const float4*)(h + (size_t)node * 256 + lane * 4);
  float ax = fabsf(v.x), ay = fabsf(v.y), az = fabsf(v.z), aw = fabsf(v.w);
  float mx = wave_reduce_max(fmaxf(fmaxf(ax, ay), fmaxf(az, aw)));
  float l1 = wave_reduce_sum(ax + ay + az + aw);
  float ss = wave_reduce_sum(dot4(v, v));
  float s = mx * (1.0f / 127.0f);
  float inv = (mx > 0.f) ? 127.0f / mx : 0.f;
  int q0 = clampq(v.x * inv), q1 = clampq(v.y * inv);
  int q2 = clampq(v.z * inv), q3 = clampq(v.w * inv);
  int w = (q0 & 0xff) | ((q1 & 0xff) << 8) | ((q2 & 0xff) << 16) | (q3 << 24);
  ((int*)(qh + (size_t)node * 256))[lane] = w;
  float l1q = s * wave_reduce_sum((float)(abs(q0) + abs(q1) + abs(q2) + abs(q3)));
  bool sp = ss > 0.5f * fmaxf(ss, EPS);
  *(float4*)(agg + (size_t)node * 256 + lane * 4) =
      sp ? v : make_float4(0.f, 0.f, 0.f, 0.f);
  if (lane == 0)
    nprop[node] = make_float4(sqrtf(ss), s, fmaxf(l1, l1q), 0.f);
}

// ====== conv, lane-per-edge: one 512-thread block per 64-node bucket ======
template <int D>
__global__ __launch_bounds__(512) void conv_lpe(
    const float* __restrict__ xf, const signed char* __restrict__ qt,
    const float4* __restrict__ nprop, const int* __restrict__ ssrc,
    const int* __restrict__ endoff, float* __restrict__ agg, int N) {
  constexpr int RB = D + 16;  // padded LDS row bytes
  constexpr int NG = D / 16;  // int4 chunks per row
  constexpr int V = D / 64;   // fp32 elems per lane (exact path)
  __shared__ signed char qtile[64 * RB];
  __shared__ float4 npd[64];
  __shared__ int eoff[65];
  const int tid = threadIdx.x;
  const int lane = tid & 63;
  const int n0 = blockIdx.x * 64;

  if (tid < 65) {
    int idx = n0 - 1 + tid;
    eoff[tid] = (idx < 0) ? 0 : endoff[min(idx, N - 1)];
  }
  if (tid >= 64 && tid < 128) {
    int i = tid - 64;
    int n = n0 + i;
    npd[i] = (n < N) ? nprop[n] : make_float4(0.f, 0.f, 0.f, 0.f);
  }
  for (int j = tid; j < 64 * NG; j += 512) {
    int r = j / NG, c = j % NG;
    int n = n0 + r;
    int4 v = (n < N) ? *(const int4*)(qt + (size_t)n * D + c * 16)
                     : make_int4(0, 0, 0, 0);
    *(int4*)(qtile + r * RB + c * 16) = v;
  }
  __syncthreads();  // qtile/npd/eoff ready

  const int bstart = eoff[0];
  const int bend = eoff[64];

  for (int base = bstart; base < bend; base += 512) {
    int e0 = base + tid;
    bool valid = e0 < bend;
    int s = valid ? ssrc[e0] : 0;
    float4 nps = valid ? nprop[s] : make_float4(0.f, 0.f, 0.f, 0.f);
    int lo = 0, hi = 63;
#pragma unroll
    for (int it = 0; it < 6; ++it) {
      int mid = (lo + hi) >> 1;
      if (e0 >= eoff[mid + 1]) lo = mid + 1; else hi = mid;
    }
    const int dloc = lo;
    float4 npdl = npd[dloc];
    const signed char* srow = qt + (size_t)s * D;
    const signed char* drow = qtile + dloc * RB;
    int id = 0;
#pragma unroll
    for (int g = 0; g < NG; ++g) {
      int4 a = *(const int4*)(srow + g * 16);
      int4 bq = *(const int4*)(drow + g * 16);
      id = sdot4i(a.x, bq.x, id);
      id = sdot4i(a.y, bq.y, id);
      id = sdot4i(a.z, bq.z, id);
      id = sdot4i(a.w, bq.w, id);
    }
    float denom = fmaxf(nps.x * npdl.x, EPS);
    float thr = 0.5f * denom;
    float approx = (nps.y * npdl.y) * (float)id;
    float m = 0.5002f * (nps.y * npdl.z + npdl.y * nps.z) + 2e-6f * denom + 1e-7f;
    bool maybe = valid && (approx > thr - m);
    unsigned long long mask = __ballot(maybe);
    while (mask) {
      int ln = __ffsll((long long)mask) - 1;
      mask &= mask - 1;
      int es = __shfl(s, ln);
      int dl = __shfl(dloc, ln);
      float nsx = __shfl(nps.x, ln);
      int dn = n0 + dl;
      float sv[V], dvv[V];
      if constexpr (V == 2) {
        float2 a = *(const float2*)(xf + (size_t)es * D + lane * 2);
        float2 b = *(const float2*)(xf + (size_t)dn * D + lane * 2);
        sv[0] = a.x; sv[1] = a.y; dvv[0] = b.x; dvv[1] = b.y;
      } else {
        float4 a = *(const float4*)(xf + (size_t)es * D + lane * 4);
        float4 b = *(const float4*)(xf + (size_t)dn * D + lane * 4);
        sv[0] = a.x; sv[1] = a.y; sv[2] = a.z; sv[3] = a.w;
        dvv[0] = b.x; dvv[1] = b.y; dvv[2] = b.z; dvv[3] = b.w;
      }
      float dx = 0.f;
#pragma unroll
      for (int q = 0; q < V; ++q) dx += sv[q] * dvv[q];
      dx = wave_reduce_sum(dx);
      float ndx = npd[dl].x;
      if (dx > 0.5f * fmaxf(nsx * ndx, EPS)) {
        float* arow = agg + (size_t)dn * D + lane * V;
#pragma unroll
        for (int q = 0; q < V; ++q) atomicAdd(&arow[q], sv[q]);
      }
    }
  }
}

// ---------------- GEMM1 via MFMA: h = relu(A @ W^T + b) -------------------
// A[Mx128] fp32 split into bf16 hi+lo (exact residual); 3-term product
// A_hi*W_hi + A_hi*W_lo + A_lo*W_hi gives ~2^-16 relative error (fp32-class).
// BM=128, BN=128, BK=32, 4 waves in 2x2, each wave 64x64 (16 acc tiles).
// LDS rows padded to 40 bf16 (80 B): frag ds_read_b128 -> bank = 20*row%32,
// rows r and r+8 pair -> 2-way (free).
__global__ __launch_bounds__(256) void gemm1_mfma(
    const float* __restrict__ A, const float* __restrict__ W,
    const float* __restrict__ bias, float* __restrict__ C, int M) {
  constexpr int K = 128, NN = 256, BM = 128, BK = 32, PK = 40;
  __shared__ unsigned short Ah[BM * PK];
  __shared__ unsigned short Al[BM * PK];
  __shared__ unsigned short Wh[BM * PK];
  __shared__ unsigned short Wl[BM * PK];
  const int tid = threadIdx.x;
  const int m0 = blockIdx.x * BM;
  const int n0 = blockIdx.y * BM;
  const int lane = tid & 63;
  const int wv = tid >> 6;
  const int wr = wv >> 1, wc = wv & 1;  // 2x2 wave grid, 64x64 each
  const int lrow = lane & 15, kg = lane >> 4;
  f32x4 acc[4][4] = {};

  for (int k0 = 0; k0 < K; k0 += BK) {
    // ---- stage: global fp32 -> split bf16 hi/lo planes in LDS ----
#pragma unroll
    for (int i = 0; i < 4; ++i) {
      int f = tid + i * 256;
      int r = f >> 3, q = f & 7;  // row 0..127, float4 index 0..7
      int gm = m0 + r;
      float4 a = (gm < M) ? *(const float4*)&A[(size_t)gm * K + k0 + q * 4]
                          : make_float4(0.f, 0.f, 0.f, 0.f);
      float4 w = *(const float4*)&W[(size_t)(n0 + r) * K + k0 + q * 4];
      unsigned int h0, h1, h2, h3, l0, l1, l2, l3;
      split_bf16(a.x, h0, l0); split_bf16(a.y, h1, l1);
      split_bf16(a.z, h2, l2); split_bf16(a.w, h3, l3);
      *(uint2*)&Ah[r * PK + q * 4] =
          make_uint2(h0 | (h1 << 16), h2 | (h3 << 16));
      *(uint2*)&Al[r * PK + q * 4] =
          make_uint2(l0 | (l1 << 16), l2 | (l3 << 16));
      split_bf16(w.x, h0, l0); split_bf16(w.y, h1, l1);
      split_bf16(w.z, h2, l2); split_bf16(w.w, h3, l3);
      *(uint2*)&Wh[r * PK + q * 4] =
          make_uint2(h0 | (h1 << 16), h2 | (h3 << 16));
      *(uint2*)&Wl[r * PK + q * 4] =
          make_uint2(l0 | (l1 << 16), l2 | (l3 << 16));
    }
    __syncthreads();
    // ---- fragments: A row = lane&15, k = (lane>>4)*8 + j ----
    bf16x8 ah[4], al[4], bh[4], bl[4];
#pragma unroll
    for (int m = 0; m < 4; ++m) {
      int row = wr * 64 + m * 16 + lrow;
      ah[m] = *(const bf16x8*)&Ah[row * PK + kg * 8];
      al[m] = *(const bf16x8*)&Al[row * PK + kg * 8];
    }
#pragma unroll
    for (int n = 0; n < 4; ++n) {
      int row = wc * 64 + n * 16 + lrow;
      bh[n] = *(const bf16x8*)&Wh[row * PK + kg * 8];
      bl[n] = *(const bf16x8*)&Wl[row * PK + kg * 8];
    }
#pragma unroll
    for (int m = 0; m < 4; ++m)
#pragma unroll
      for (int n = 0; n < 4; ++n) {
        acc[m][n] = __builtin_amdgcn_mfma_f32_16x16x32_bf16(ah[m], bh[n],
                                                            acc[m][n], 0, 0, 0);
        acc[m][n] = __builtin_amdgcn_mfma_f32_16x16x32_bf16(ah[m], bl[n],
                                                            acc[m][n], 0, 0, 0);
        acc[m][n] = __builtin_amdgcn_mfma_f32_16x16x32_bf16(al[m], bh[n],
                                                            acc[m][n], 0, 0, 0);
      }
    __syncthreads();
  }

  // ---- epilogue: C/D col = lane&15, row = (lane>>4)*4 + reg ----
#pragma unroll
  for (int n = 0; n < 4; ++n) {
    int gc = n0 + wc * 64 + n * 16 + lrow;
    float bv = bias[gc];
#pragma unroll
    for (int m = 0; m < 4; ++m) {
      int gr0 = m0 + wr * 64 + m * 16 + kg * 4;
#pragma unroll
      for (int r = 0; r < 4; ++r) {
        int gm = gr0 + r;
        if (gm < M) {
          float v = acc[m][n][r] + bv;
          C[(size_t)gm * NN + gc] = fmaxf(v, 0.f);
        }
      }
    }
  }
}

// ------- GEMM2 fused with log_softmax: out = lsm(A @ W^T + b), BN=64 ------
// Same conflict-free staging (pads 132/68, 16-row write mapping).
__global__ __launch_bounds__(256) void gemm2_lsm(
    const float* __restrict__ A, const float* __restrict__ W,
    const float* __restrict__ bias, float* __restrict__ out, int M, int K) {
  constexpr int BM = 128, BN = 64, BK = 32, TM = 4;
  constexpr int NTX = BN / 8;     // 8
  constexpr int KQ = BK / 4;      // 8
  constexpr int L4A = BM * KQ / 256;  // 4
  constexpr int L4B = BN * KQ / 256;  // 2
  constexpr int PM = BM + 4;      // 132
  constexpr int PN = BN + 4;      // 68
  __shared__ float smem[BM * 65];     // 8320 floats >= BK*PM + BK*PN (6400)
  float* As = smem;                   // [BK][PM]
  float* Bs = smem + BK * PM;         // [BK][PN]
  const int tid = threadIdx.x;
  const int m0 = blockIdx.x * BM;
  const int tx = tid % NTX;
  const int ty = tid / NTX;
  const int ms = ty * TM;
  const int ns = tx * 4;
  float acc[TM][8] = {};
  for (int k0 = 0; k0 < K; k0 += BK) {
#pragma unroll
    for (int t = 0; t < L4A; ++t) {
      int f = tid + t * 256;
      int row = (f >> 2) % BM;
      int kq = (f & 3) + 4 * (f / (4 * BM));
      int gm = m0 + row;
      float4 a = (gm < M) ? *(const float4*)&A[(size_t)gm * K + k0 + kq * 4]
                          : make_float4(0.f, 0.f, 0.f, 0.f);
      As[(kq * 4 + 0) * PM + row] = a.x; As[(kq * 4 + 1) * PM + row] = a.y;
      As[(kq * 4 + 2) * PM + row] = a.z; As[(kq * 4 + 3) * PM + row] = a.w;
    }
#pragma unroll
    for (int t = 0; t < L4B; ++t) {
      int f = tid + t * 256;
      int row = (f >> 2) % BN;
      int kq = (f & 3) + 4 * (f / (4 * BN));
      float4 b = *(const float4*)&W[(size_t)row * K + k0 + kq * 4];
      Bs[(kq * 4 + 0) * PN + row] = b.x; Bs[(kq * 4 + 1) * PN + row] = b.y;
      Bs[(kq * 4 + 2) * PN + row] = b.z; Bs[(kq * 4 + 3) * PN + row] = b.w;
    }
    __syncthreads();
#pragma unroll
    for (int kk = 0; kk < BK; ++kk) {
      float4 a4 = *(const float4*)&As[kk * PM + ms];
      float av[4] = {a4.x, a4.y, a4.z, a4.w};
      float4 b0 = *(const float4*)&Bs[kk * PN + ns];
      float4 b1 = *(const float4*)&Bs[kk * PN + ns + 32];
      float bv[8] = {b0.x, b0.y, b0.z, b0.w, b1.x, b1.y, b1.z, b1.w};
#pragma unroll
      for (int i = 0; i < TM; ++i)
#pragma unroll
        for (int j = 0; j < 8; ++j) acc[i][j] += av[i] * bv[j];
    }
    __syncthreads();
  }
  float4 bb0 = *(const float4*)&bias[ns];
  float4 bb1 = *(const float4*)&bias[32 + ns];
  float bv[8] = {bb0.x, bb0.y, bb0.z, bb0.w, bb1.x, bb1.y, bb1.z, bb1.w};
#pragma unroll
  for (int i = 0; i < TM; ++i) {
    int row = ms + i;
#pragma unroll
    for (int grp = 0; grp < 2; ++grp)
#pragma unroll
      for (int j = 0; j < 4; ++j)
        smem[row * 65 + grp * 32 + ns + j] = acc[i][grp * 4 + j] + bv[grp * 4 + j];
  }
  __syncthreads();
  int w = tid >> 6, lane = tid & 63;
  for (int r = w; r < BM; r += 4) {
    int gm = m0 + r;
    if (gm >= M) continue;
    float v = smem[r * 65 + lane];
    float mx = wave_reduce_max(v);
    float e = expf(v - mx);
    float sm = wave_reduce_sum(e);
    out[(size_t)gm * 64 + lane] = v - mx - logf(sm);
  }
}

extern "C" void kernel_launch(void* const* d_in, const int* in_sizes, int n_in,
                              void* d_out, int out_size, void* d_ws,
                              size_t ws_size, hipStream_t stream) {
  const float* x  = (const float*)d_in[0];
  const int* eidx = (const int*)d_in[1];
  const float* W1 = (const float*)d_in[2];
  const float* b1 = (const float*)d_in[3];
  const float* W2 = (const float*)d_in[4];
  const float* b2 = (const float*)d_in[5];
  float* out = (float*)d_out;

  const int N = in_sizes[0] / 128;  // 50000
  const int E = in_sizes[1] / 2;    // 800000
  const int* src = eidx;
  const int* dst = eidx + E;

  const int nbuck = (N + 63) / 64;         // 782
  const int ntot = nbuck * NB_SORT;        // 200192
  const int nblk2 = (ntot + 1023) / 1024;  // 196

  float* agg    = (float*)d_ws;
  float* h      = agg + (size_t)N * 256;
  float4* npx   = (float4*)(h + (size_t)N * 256);
  float4* nph   = npx + N;
  int* S        = (int*)(nph + N);
  int* bsum     = S + ntot;
  int* ssrc     = bsum + 256;
  int* endoff   = ssrc + E;
  signed char* qh = (signed char*)(endoff + N);
  int2* epair   = (int2*)h;                              // overlap (6.4 MB)
  signed char* qx = (signed char*)(h + (size_t)N * 64);  // overlap (6.4 MB)

  // ---- build CSR (by dst) with LDS-only atomics ----
  hist_coarse<<<NB_SORT, 256, 0, stream>>>(dst, S, E, nbuck);
  scan_local<<<nblk2, 256, 0, stream>>>(S, bsum, ntot);
  scan_bsum<<<1, 256, 0, stream>>>(bsum, nblk2);
  add_bsum<<<(ntot + 255) / 256, 256, 0, stream>>>(S, bsum, ntot);
  scatter_coarse<<<NB_SORT, 256, 0, stream>>>(src, dst, S, epair, E, nbuck);
  fine_sort<<<nbuck, 256, 0, stream>>>(epair, S, ssrc, endoff, E, nbuck, N);

  // ---- layer 1 (D=128) ----
  prep_x<<<(N + 3) / 4, 256, 0, stream>>>(x, qx, npx, agg, N);
  conv_lpe<128><<<nbuck, 512, 0, stream>>>(x, qx, npx, ssrc, endoff, agg, N);
  gemm1_mfma<<<dim3((N + 127) / 128, 2), 256, 0, stream>>>(agg, W1, b1, h, N);

  // ---- layer 2 (D=256) ----
  prep_h<<<(N + 3) / 4, 256, 0, stream>>>(h, qh, nph, agg, N);
  conv_lpe<256><<<nbuck, 512, 0, stream>>>(h, qh, nph, ssrc, endoff, agg, N);
  gemm2_lsm<<<dim3((N + 127) / 128), 256, 0, stream>>>(agg, W2, b2, out, N,
                                                       256);
}

// Round 2
// 300.570 us; speedup vs baseline: 1.0972x; 1.0721x over previous
//
#include <hip/hip_runtime.h>
#include <math.h>

#define EPS 1e-8f
#define NB_SORT 256  // blocks in coarse sort phases

#if defined(__has_builtin)
#if __has_builtin(__builtin_amdgcn_sdot4)
#define HAVE_SDOT4 1
#endif
#endif

typedef __attribute__((ext_vector_type(8))) short bf16x8;
typedef __attribute__((ext_vector_type(4))) float f32x4;

__device__ __forceinline__ int sdot4i(int a, int b, int c) {
#ifdef HAVE_SDOT4
  return __builtin_amdgcn_sdot4(a, b, c, false);
#else
  return c + ((int)(signed char)(a)) * ((int)(signed char)(b)) +
         ((int)(signed char)(a >> 8)) * ((int)(signed char)(b >> 8)) +
         ((int)(signed char)(a >> 16)) * ((int)(signed char)(b >> 16)) +
         (a >> 24) * (b >> 24);
#endif
}

__device__ __forceinline__ float wave_reduce_sum(float v) {
#pragma unroll
  for (int off = 32; off > 0; off >>= 1)
    v += __shfl_xor(v, off, 64);
  return v;
}

__device__ __forceinline__ float wave_reduce_max(float v) {
#pragma unroll
  for (int off = 32; off > 0; off >>= 1)
    v = fmaxf(v, __shfl_xor(v, off, 64));
  return v;
}

__device__ __forceinline__ float dot4(float4 a, float4 b) {
  return a.x * b.x + a.y * b.y + a.z * b.z + a.w * b.w;
}

__device__ __forceinline__ int clampq(float q) {
  int i = (int)rintf(q);
  return i < -127 ? -127 : (i > 127 ? 127 : i);
}

// split fp32 into bf16 hi (truncate) + bf16 lo (exact residual, truncate)
// |x - (hi+lo)| <= 2^-16 |x|  (residual x-hi is exactly representable)
__device__ __forceinline__ void split_bf16(float x, unsigned int& hi,
                                           unsigned int& lo) {
  unsigned int u = __float_as_uint(x);
  hi = u >> 16;
  float hf = __uint_as_float(u & 0xFFFF0000u);
  float r = x - hf;
  lo = __float_as_uint(r) >> 16;
}

// ============ CSR build: 2-level bucket sort, LDS atomics only ============
__global__ __launch_bounds__(256) void hist_coarse(const int* __restrict__ dst,
                                                   int* __restrict__ hist_blk,
                                                   int E, int nbuck) {
  __shared__ int lh[1024];
  int t = threadIdx.x, blk = blockIdx.x;
  for (int i = t; i < nbuck; i += 256) lh[i] = 0;
  __syncthreads();
  int ch = (E + NB_SORT - 1) / NB_SORT;
  int lo = blk * ch, hi = min(E, lo + ch);
  for (int e = lo + t; e < hi; e += 256) atomicAdd(&lh[dst[e] >> 6], 1);
  __syncthreads();
  for (int i = t; i < nbuck; i += 256) hist_blk[i * NB_SORT + blk] = lh[i];
}

__global__ __launch_bounds__(256) void scan_local(int* __restrict__ hist,
                                                  int* __restrict__ bsum,
                                                  int nb) {
  __shared__ int tsum[256];
  int t = threadIdx.x;
  int base = blockIdx.x * 1024 + t * 4;
  int v0 = 0, v1 = 0, v2 = 0, v3 = 0;
  if (base + 3 < nb) {
    int4 q = *(const int4*)&hist[base];
    v0 = q.x; v1 = q.y; v2 = q.z; v3 = q.w;
  } else {
    if (base + 0 < nb) v0 = hist[base + 0];
    if (base + 1 < nb) v1 = hist[base + 1];
    if (base + 2 < nb) v2 = hist[base + 2];
  }
  tsum[t] = v0 + v1 + v2 + v3;
  __syncthreads();
  for (int off = 1; off < 256; off <<= 1) {
    int u = 0;
    if (t >= off) u = tsum[t - off];
    __syncthreads();
    if (t >= off) tsum[t] += u;
    __syncthreads();
  }
  int excl = (t == 0) ? 0 : tsum[t - 1];
  int e0 = excl, e1 = excl + v0, e2 = e1 + v1, e3 = e2 + v2;
  if (base + 3 < nb) {
    *(int4*)&hist[base] = make_int4(e0, e1, e2, e3);
  } else {
    if (base + 0 < nb) hist[base + 0] = e0;
    if (base + 1 < nb) hist[base + 1] = e1;
    if (base + 2 < nb) hist[base + 2] = e2;
  }
  if (t == 255) bsum[blockIdx.x] = tsum[255];
}

__global__ __launch_bounds__(256) void scan_bsum(int* __restrict__ bsum,
                                                 int nblk) {
  __shared__ int sh[256];
  int t = threadIdx.x;
  sh[t] = (t < nblk) ? bsum[t] : 0;
  __syncthreads();
  for (int off = 1; off < 256; off <<= 1) {
    int u = 0;
    if (t >= off) u = sh[t - off];
    __syncthreads();
    if (t >= off) sh[t] += u;
    __syncthreads();
  }
  if (t < nblk) bsum[t] = (t == 0) ? 0 : sh[t - 1];
}

__global__ __launch_bounds__(256) void add_bsum(int* __restrict__ hist,
                                                const int* __restrict__ bsum,
                                                int nb) {
  int i = blockIdx.x * blockDim.x + threadIdx.x;
  if (i < nb) hist[i] += bsum[i >> 10];
}

__global__ __launch_bounds__(256) void scatter_coarse(
    const int* __restrict__ src, const int* __restrict__ dst,
    const int* __restrict__ S, int2* __restrict__ epair, int E, int nbuck) {
  __shared__ int lb[1024];
  int t = threadIdx.x, blk = blockIdx.x;
  for (int i = t; i < nbuck; i += 256) lb[i] = S[i * NB_SORT + blk];
  __syncthreads();
  int ch = (E + NB_SORT - 1) / NB_SORT;
  int lo = blk * ch, hi = min(E, lo + ch);
  for (int e = lo + t; e < hi; e += 256) {
    int d = dst[e];
    int pos = atomicAdd(&lb[d >> 6], 1);
    epair[pos] = make_int2(src[e], d);
  }
}

__global__ __launch_bounds__(256) void fine_sort(
    const int2* __restrict__ epair, const int* __restrict__ S,
    int* __restrict__ ssrc, int* __restrict__ endoff, int E, int nbuck,
    int N) {
  __shared__ int fh[64];
  __shared__ int cur[64];
  int b = blockIdx.x, t = threadIdx.x;
  int bstart = S[b * NB_SORT];
  int bend = (b + 1 < nbuck) ? S[(b + 1) * NB_SORT] : E;
  if (t < 64) fh[t] = 0;
  __syncthreads();
  for (int e = bstart + t; e < bend; e += 256)
    atomicAdd(&fh[epair[e].y & 63], 1);
  __syncthreads();
  if (t < 64) {
    int v = fh[t];
    int incl = v;
#pragma unroll
    for (int off = 1; off < 64; off <<= 1) {
      int u = __shfl_up(incl, off, 64);
      if (t >= off) incl += u;
    }
    cur[t] = incl - v;
    int d = b * 64 + t;
    if (d < N) endoff[d] = bstart + incl;
  }
  __syncthreads();
  for (int e = bstart + t; e < bend; e += 256) {
    int2 p = epair[e];
    int pos = atomicAdd(&cur[p.y & 63], 1);
    ssrc[bstart + pos] = p.x;
  }
}

// ============ prep: quantize + node props + self-loop agg init ============
__global__ __launch_bounds__(256) void prep_x(const float* __restrict__ x,
                                              signed char* __restrict__ qx,
                                              float4* __restrict__ nprop,
                                              float* __restrict__ agg,
                                              int N) {
  int node = (int)((blockIdx.x * blockDim.x + threadIdx.x) >> 6);
  int lane = threadIdx.x & 63;
  if (node >= N) return;
  float2 v = *(const float2*)(x + (size_t)node * 128 + lane * 2);
  float ax = fabsf(v.x), ay = fabsf(v.y);
  float mx = wave_reduce_max(fmaxf(ax, ay));
  float l1 = wave_reduce_sum(ax + ay);
  float ss = wave_reduce_sum(v.x * v.x + v.y * v.y);
  float s = mx * (1.0f / 127.0f);
  float inv = (mx > 0.f) ? 127.0f / mx : 0.f;
  int q0 = clampq(v.x * inv), q1 = clampq(v.y * inv);
  unsigned short w = (unsigned short)((q0 & 0xff) | ((q1 & 0xff) << 8));
  ((unsigned short*)(qx + (size_t)node * 128))[lane] = w;
  float l1q = s * wave_reduce_sum((float)(abs(q0) + abs(q1)));
  bool sp = ss > 0.5f * fmaxf(ss, EPS);
  *(float2*)(agg + (size_t)node * 128 + lane * 2) =
      sp ? v : make_float2(0.f, 0.f);
  if (lane == 0)
    nprop[node] = make_float4(sqrtf(ss), s, fmaxf(l1, l1q), 0.f);
}

__global__ __launch_bounds__(256) void prep_h(const float* __restrict__ h,
                                              signed char* __restrict__ qh,
                                              float4* __restrict__ nprop,
                                              float* __restrict__ agg,
                                              int N) {
  int node = (int)((blockIdx.x * blockDim.x + threadIdx.x) >> 6);
  int lane = threadIdx.x & 63;
  if (node >= N) return;
  float4 v = *(const float4*)(h + (size_t)node * 256 + lane * 4);
  float ax = fabsf(v.x), ay = fabsf(v.y), az = fabsf(v.z), aw = fabsf(v.w);
  float mx = wave_reduce_max(fmaxf(fmaxf(ax, ay), fmaxf(az, aw)));
  float l1 = wave_reduce_sum(ax + ay + az + aw);
  float ss = wave_reduce_sum(dot4(v, v));
  float s = mx * (1.0f / 127.0f);
  float inv = (mx > 0.f) ? 127.0f / mx : 0.f;
  int q0 = clampq(v.x * inv), q1 = clampq(v.y * inv);
  int q2 = clampq(v.z * inv), q3 = clampq(v.w * inv);
  int w = (q0 & 0xff) | ((q1 & 0xff) << 8) | ((q2 & 0xff) << 16) | (q3 << 24);
  ((int*)(qh + (size_t)node * 256))[lane] = w;
  float l1q = s * wave_reduce_sum((float)(abs(q0) + abs(q1) + abs(q2) + abs(q3)));
  bool sp = ss > 0.5f * fmaxf(ss, EPS);
  *(float4*)(agg + (size_t)node * 256 + lane * 4) =
      sp ? v : make_float4(0.f, 0.f, 0.f, 0.f);
  if (lane == 0)
    nprop[node] = make_float4(sqrtf(ss), s, fmaxf(l1, l1q), 0.f);
}

// ====== conv, lane-per-edge: one 512-thread block per 64-node bucket ======
template <int D>
__global__ __launch_bounds__(512) void conv_lpe(
    const float* __restrict__ xf, const signed char* __restrict__ qt,
    const float4* __restrict__ nprop, const int* __restrict__ ssrc,
    const int* __restrict__ endoff, float* __restrict__ agg, int N) {
  constexpr int RB = D + 16;  // padded LDS row bytes
  constexpr int NG = D / 16;  // int4 chunks per row
  constexpr int V = D / 64;   // fp32 elems per lane (exact path)
  __shared__ signed char qtile[64 * RB];
  __shared__ float4 npd[64];
  __shared__ int eoff[65];
  const int tid = threadIdx.x;
  const int lane = tid & 63;
  const int n0 = blockIdx.x * 64;

  if (tid < 65) {
    int idx = n0 - 1 + tid;
    eoff[tid] = (idx < 0) ? 0 : endoff[min(idx, N - 1)];
  }
  if (tid >= 64 && tid < 128) {
    int i = tid - 64;
    int n = n0 + i;
    npd[i] = (n < N) ? nprop[n] : make_float4(0.f, 0.f, 0.f, 0.f);
  }
  for (int j = tid; j < 64 * NG; j += 512) {
    int r = j / NG, c = j % NG;
    int n = n0 + r;
    int4 v = (n < N) ? *(const int4*)(qt + (size_t)n * D + c * 16)
                     : make_int4(0, 0, 0, 0);
    *(int4*)(qtile + r * RB + c * 16) = v;
  }
  __syncthreads();  // qtile/npd/eoff ready

  const int bstart = eoff[0];
  const int bend = eoff[64];

  for (int base = bstart; base < bend; base += 512) {
    int e0 = base + tid;
    bool valid = e0 < bend;
    int s = valid ? ssrc[e0] : 0;
    float4 nps = valid ? nprop[s] : make_float4(0.f, 0.f, 0.f, 0.f);
    int lo = 0, hi = 63;
#pragma unroll
    for (int it = 0; it < 6; ++it) {
      int mid = (lo + hi) >> 1;
      if (e0 >= eoff[mid + 1]) lo = mid + 1; else hi = mid;
    }
    const int dloc = lo;
    float4 npdl = npd[dloc];
    const signed char* srow = qt + (size_t)s * D;
    const signed char* drow = qtile + dloc * RB;
    int id = 0;
#pragma unroll
    for (int g = 0; g < NG; ++g) {
      int4 a = *(const int4*)(srow + g * 16);
      int4 bq = *(const int4*)(drow + g * 16);
      id = sdot4i(a.x, bq.x, id);
      id = sdot4i(a.y, bq.y, id);
      id = sdot4i(a.z, bq.z, id);
      id = sdot4i(a.w, bq.w, id);
    }
    float denom = fmaxf(nps.x * npdl.x, EPS);
    float thr = 0.5f * denom;
    float approx = (nps.y * npdl.y) * (float)id;
    float m = 0.5002f * (nps.y * npdl.z + npdl.y * nps.z) + 2e-6f * denom + 1e-7f;
    bool maybe = valid && (approx > thr - m);
    unsigned long long mask = __ballot(maybe);
    while (mask) {
      int ln = __ffsll((long long)mask) - 1;
      mask &= mask - 1;
      int es = __shfl(s, ln);
      int dl = __shfl(dloc, ln);
      float nsx = __shfl(nps.x, ln);
      int dn = n0 + dl;
      float sv[V], dvv[V];
      if constexpr (V == 2) {
        float2 a = *(const float2*)(xf + (size_t)es * D + lane * 2);
        float2 b = *(const float2*)(xf + (size_t)dn * D + lane * 2);
        sv[0] = a.x; sv[1] = a.y; dvv[0] = b.x; dvv[1] = b.y;
      } else {
        float4 a = *(const float4*)(xf + (size_t)es * D + lane * 4);
        float4 b = *(const float4*)(xf + (size_t)dn * D + lane * 4);
        sv[0] = a.x; sv[1] = a.y; sv[2] = a.z; sv[3] = a.w;
        dvv[0] = b.x; dvv[1] = b.y; dvv[2] = b.z; dvv[3] = b.w;
      }
      float dx = 0.f;
#pragma unroll
      for (int q = 0; q < V; ++q) dx += sv[q] * dvv[q];
      dx = wave_reduce_sum(dx);
      float ndx = npd[dl].x;
      if (dx > 0.5f * fmaxf(nsx * ndx, EPS)) {
        float* arow = agg + (size_t)dn * D + lane * V;
#pragma unroll
        for (int q = 0; q < V; ++q) atomicAdd(&arow[q], sv[q]);
      }
    }
  }
}

// ---------------- GEMM1 via MFMA: h = relu(A @ W^T + b) -------------------
// A[Mx128] fp32 split into bf16 hi+lo (exact residual); 3-term product
// A_hi*W_hi + A_hi*W_lo + A_lo*W_hi gives ~2^-16 relative error (fp32-class).
// BM=128, BN=128, BK=32, 4 waves in 2x2, each wave 64x64 (16 acc tiles).
__global__ __launch_bounds__(256) void gemm1_mfma(
    const float* __restrict__ A, const float* __restrict__ W,
    const float* __restrict__ bias, float* __restrict__ C, int M) {
  constexpr int K = 128, NN = 256, BM = 128, BK = 32, PK = 40;
  __shared__ unsigned short Ah[BM * PK];
  __shared__ unsigned short Al[BM * PK];
  __shared__ unsigned short Wh[BM * PK];
  __shared__ unsigned short Wl[BM * PK];
  const int tid = threadIdx.x;
  const int m0 = blockIdx.x * BM;
  const int n0 = blockIdx.y * BM;
  const int lane = tid & 63;
  const int wv = tid >> 6;
  const int wr = wv >> 1, wc = wv & 1;  // 2x2 wave grid, 64x64 each
  const int lrow = lane & 15, kg = lane >> 4;
  f32x4 acc[4][4] = {};

  for (int k0 = 0; k0 < K; k0 += BK) {
    // ---- stage: global fp32 -> split bf16 hi/lo planes in LDS ----
#pragma unroll
    for (int i = 0; i < 4; ++i) {
      int f = tid + i * 256;
      int r = f >> 3, q = f & 7;  // row 0..127, float4 index 0..7
      int gm = m0 + r;
      float4 a = (gm < M) ? *(const float4*)&A[(size_t)gm * K + k0 + q * 4]
                          : make_float4(0.f, 0.f, 0.f, 0.f);
      float4 w = *(const float4*)&W[(size_t)(n0 + r) * K + k0 + q * 4];
      unsigned int h0, h1, h2, h3, l0, l1, l2, l3;
      split_bf16(a.x, h0, l0); split_bf16(a.y, h1, l1);
      split_bf16(a.z, h2, l2); split_bf16(a.w, h3, l3);
      *(uint2*)&Ah[r * PK + q * 4] =
          make_uint2(h0 | (h1 << 16), h2 | (h3 << 16));
      *(uint2*)&Al[r * PK + q * 4] =
          make_uint2(l0 | (l1 << 16), l2 | (l3 << 16));
      split_bf16(w.x, h0, l0); split_bf16(w.y, h1, l1);
      split_bf16(w.z, h2, l2); split_bf16(w.w, h3, l3);
      *(uint2*)&Wh[r * PK + q * 4] =
          make_uint2(h0 | (h1 << 16), h2 | (h3 << 16));
      *(uint2*)&Wl[r * PK + q * 4] =
          make_uint2(l0 | (l1 << 16), l2 | (l3 << 16));
    }
    __syncthreads();
    // ---- fragments: A row = lane&15, k = (lane>>4)*8 + j ----
    bf16x8 ah[4], al[4], bh[4], bl[4];
#pragma unroll
    for (int m = 0; m < 4; ++m) {
      int row = wr * 64 + m * 16 + lrow;
      ah[m] = *(const bf16x8*)&Ah[row * PK + kg * 8];
      al[m] = *(const bf16x8*)&Al[row * PK + kg * 8];
    }
#pragma unroll
    for (int n = 0; n < 4; ++n) {
      int row = wc * 64 + n * 16 + lrow;
      bh[n] = *(const bf16x8*)&Wh[row * PK + kg * 8];
      bl[n] = *(const bf16x8*)&Wl[row * PK + kg * 8];
    }
#pragma unroll
    for (int m = 0; m < 4; ++m)
#pragma unroll
      for (int n = 0; n < 4; ++n) {
        acc[m][n] = __builtin_amdgcn_mfma_f32_16x16x32_bf16(ah[m], bh[n],
                                                            acc[m][n], 0, 0, 0);
        acc[m][n] = __builtin_amdgcn_mfma_f32_16x16x32_bf16(ah[m], bl[n],
                                                            acc[m][n], 0, 0, 0);
        acc[m][n] = __builtin_amdgcn_mfma_f32_16x16x32_bf16(al[m], bh[n],
                                                            acc[m][n], 0, 0, 0);
      }
    __syncthreads();
  }

  // ---- epilogue: C/D col = lane&15, row = (lane>>4)*4 + reg ----
#pragma unroll
  for (int n = 0; n < 4; ++n) {
    int gc = n0 + wc * 64 + n * 16 + lrow;
    float bv = bias[gc];
#pragma unroll
    for (int m = 0; m < 4; ++m) {
      int gr0 = m0 + wr * 64 + m * 16 + kg * 4;
#pragma unroll
      for (int r = 0; r < 4; ++r) {
        int gm = gr0 + r;
        if (gm < M) {
          float v = acc[m][n][r] + bv;
          C[(size_t)gm * NN + gc] = fmaxf(v, 0.f);
        }
      }
    }
  }
}

// ---- pre-split W2 (64x256 fp32) into bf16 hi/lo planes in workspace ----
__global__ __launch_bounds__(256) void split_w2(
    const float* __restrict__ W, unsigned short* __restrict__ Wh,
    unsigned short* __restrict__ Wl, int total4) {
  int i = blockIdx.x * 256 + threadIdx.x;
  if (i >= total4) return;
  float4 w = ((const float4*)W)[i];
  unsigned int h0, h1, h2, h3, l0, l1, l2, l3;
  split_bf16(w.x, h0, l0); split_bf16(w.y, h1, l1);
  split_bf16(w.z, h2, l2); split_bf16(w.w, h3, l3);
  ((uint2*)Wh)[i] = make_uint2(h0 | (h1 << 16), h2 | (h3 << 16));
  ((uint2*)Wl)[i] = make_uint2(l0 | (l1 << 16), l2 | (l3 << 16));
}

// ------ GEMM2 via MFMA, LDS-free, fused log_softmax: out[Mx64] ------------
// N=64 = one wave's col footprint, K=256. Each A element used exactly once
// -> no LDS staging: lanes load their MFMA A-fragment straight from global
// (coalesced 16-row x 128B windows) and split to bf16 hi/lo in-register.
// W fragments come from pre-split L2-resident planes. Softmax fully
// in-register: each output row lives in 16 lanes x 4 regs (C/D layout),
// reduced via shfl_xor(8/4/2/1).
__global__ __launch_bounds__(256) void gemm2_mfma_lsm(
    const float* __restrict__ A, const unsigned short* __restrict__ Wh,
    const unsigned short* __restrict__ Wl, const float* __restrict__ bias,
    float* __restrict__ out, int M) {
  constexpr int K = 256;
  const int tid = threadIdx.x;
  const int lane = tid & 63;
  const int wv = tid >> 6;
  const int lrow = lane & 15, kg = lane >> 4;
  const int r0 = blockIdx.x * 128 + wv * 32;  // wave's first row
  f32x4 acc[2][4] = {};

  for (int k0 = 0; k0 < K; k0 += 32) {
    bf16x8 ah[2], al[2];
#pragma unroll
    for (int m = 0; m < 2; ++m) {
      int row = r0 + m * 16 + lrow;  // rows up to 50047 stay inside ws (h)
      const float* ap = A + (size_t)row * K + k0 + kg * 8;
      float4 a0 = *(const float4*)ap;
      float4 a1 = *(const float4*)(ap + 4);
      unsigned int hh[8], ll[8];
      split_bf16(a0.x, hh[0], ll[0]); split_bf16(a0.y, hh[1], ll[1]);
      split_bf16(a0.z, hh[2], ll[2]); split_bf16(a0.w, hh[3], ll[3]);
      split_bf16(a1.x, hh[4], ll[4]); split_bf16(a1.y, hh[5], ll[5]);
      split_bf16(a1.z, hh[6], ll[6]); split_bf16(a1.w, hh[7], ll[7]);
      bf16x8 th, tl;
#pragma unroll
      for (int j = 0; j < 8; ++j) {
        th[j] = (short)hh[j];
        tl[j] = (short)ll[j];
      }
      ah[m] = th;
      al[m] = tl;
    }
    bf16x8 bh[4], bl[4];
#pragma unroll
    for (int n = 0; n < 4; ++n) {
      int wrow = n * 16 + lrow;
      bh[n] = *(const bf16x8*)&Wh[(size_t)wrow * K + k0 + kg * 8];
      bl[n] = *(const bf16x8*)&Wl[(size_t)wrow * K + k0 + kg * 8];
    }
#pragma unroll
    for (int m = 0; m < 2; ++m)
#pragma unroll
      for (int n = 0; n < 4; ++n) {
        acc[m][n] = __builtin_amdgcn_mfma_f32_16x16x32_bf16(ah[m], bh[n],
                                                            acc[m][n], 0, 0, 0);
        acc[m][n] = __builtin_amdgcn_mfma_f32_16x16x32_bf16(ah[m], bl[n],
                                                            acc[m][n], 0, 0, 0);
        acc[m][n] = __builtin_amdgcn_mfma_f32_16x16x32_bf16(al[m], bh[n],
                                                            acc[m][n], 0, 0, 0);
      }
  }

  float bv[4];
#pragma unroll
  for (int n = 0; n < 4; ++n) bv[n] = bias[n * 16 + lrow];
#pragma unroll
  for (int m = 0; m < 2; ++m)
#pragma unroll
    for (int r = 0; r < 4; ++r) {
      int row = r0 + m * 16 + kg * 4 + r;
      float v[4];
      float mx = -1e30f;
#pragma unroll
      for (int n = 0; n < 4; ++n) {
        v[n] = acc[m][n][r] + bv[n];
        mx = fmaxf(mx, v[n]);
      }
#pragma unroll
      for (int off = 8; off > 0; off >>= 1)
        mx = fmaxf(mx, __shfl_xor(mx, off, 64));
      float s = 0.f;
#pragma unroll
      for (int n = 0; n < 4; ++n) s += expf(v[n] - mx);
#pragma unroll
      for (int off = 8; off > 0; off >>= 1) s += __shfl_xor(s, off, 64);
      float lg = logf(s);
      if (row < M) {
#pragma unroll
        for (int n = 0; n < 4; ++n)
          out[(size_t)row * 64 + n * 16 + lrow] = v[n] - mx - lg;
      }
    }
}

extern "C" void kernel_launch(void* const* d_in, const int* in_sizes, int n_in,
                              void* d_out, int out_size, void* d_ws,
                              size_t ws_size, hipStream_t stream) {
  const float* x  = (const float*)d_in[0];
  const int* eidx = (const int*)d_in[1];
  const float* W1 = (const float*)d_in[2];
  const float* b1 = (const float*)d_in[3];
  const float* W2 = (const float*)d_in[4];
  const float* b2 = (const float*)d_in[5];
  float* out = (float*)d_out;

  const int N = in_sizes[0] / 128;  // 50000
  const int E = in_sizes[1] / 2;    // 800000
  const int* src = eidx;
  const int* dst = eidx + E;

  const int nbuck = (N + 63) / 64;         // 782
  const int ntot = nbuck * NB_SORT;        // 200192
  const int nblk2 = (ntot + 1023) / 1024;  // 196

  float* agg    = (float*)d_ws;
  float* h      = agg + (size_t)N * 256;
  float4* npx   = (float4*)(h + (size_t)N * 256);
  float4* nph   = npx + N;
  int* S        = (int*)(nph + N);
  int* bsum     = S + ntot;
  int* ssrc     = bsum + 256;
  int* endoff   = ssrc + E;
  signed char* qh = (signed char*)(endoff + N);
  unsigned short* W2h = (unsigned short*)(qh + (size_t)N * 256);
  unsigned short* W2l = W2h + 64 * 256;
  int2* epair   = (int2*)h;                              // overlap (6.4 MB)
  signed char* qx = (signed char*)(h + (size_t)N * 64);  // overlap (6.4 MB)

  // ---- pre-split W2 into bf16 hi/lo planes (L2-resident afterwards) ----
  split_w2<<<16, 256, 0, stream>>>(W2, W2h, W2l, 64 * 256 / 4);

  // ---- build CSR (by dst) with LDS-only atomics ----
  hist_coarse<<<NB_SORT, 256, 0, stream>>>(dst, S, E, nbuck);
  scan_local<<<nblk2, 256, 0, stream>>>(S, bsum, ntot);
  scan_bsum<<<1, 256, 0, stream>>>(bsum, nblk2);
  add_bsum<<<(ntot + 255) / 256, 256, 0, stream>>>(S, bsum, ntot);
  scatter_coarse<<<NB_SORT, 256, 0, stream>>>(src, dst, S, epair, E, nbuck);
  fine_sort<<<nbuck, 256, 0, stream>>>(epair, S, ssrc, endoff, E, nbuck, N);

  // ---- layer 1 (D=128) ----
  prep_x<<<(N + 3) / 4, 256, 0, stream>>>(x, qx, npx, agg, N);
  conv_lpe<128><<<nbuck, 512, 0, stream>>>(x, qx, npx, ssrc, endoff, agg, N);
  gemm1_mfma<<<dim3((N + 127) / 128, 2), 256, 0, stream>>>(agg, W1, b1, h, N);

  // ---- layer 2 (D=256) ----
  prep_h<<<(N + 3) / 4, 256, 0, stream>>>(h, qh, nph, agg, N);
  conv_lpe<256><<<nbuck, 512, 0, stream>>>(h, qh, nph, ssrc, endoff, agg, N);
  gemm2_mfma_lsm<<<dim3((N + 127) / 128), 256, 0, stream>>>(agg, W2h, W2l, b2,
                                                            out, N);
}

// Round 3
// 296.150 us; speedup vs baseline: 1.1136x; 1.0149x over previous
//
#include <hip/hip_runtime.h>
#include <math.h>

#define EPS 1e-8f
#define NB_SORT 256  // blocks in coarse sort phases

#if defined(__has_builtin)
#if __has_builtin(__builtin_amdgcn_sdot4)
#define HAVE_SDOT4 1
#endif
#endif

typedef __attribute__((ext_vector_type(8))) short bf16x8;
typedef __attribute__((ext_vector_type(4))) float f32x4;

__device__ __forceinline__ int sdot4i(int a, int b, int c) {
#ifdef HAVE_SDOT4
  return __builtin_amdgcn_sdot4(a, b, c, false);
#else
  return c + ((int)(signed char)(a)) * ((int)(signed char)(b)) +
         ((int)(signed char)(a >> 8)) * ((int)(signed char)(b >> 8)) +
         ((int)(signed char)(a >> 16)) * ((int)(signed char)(b >> 16)) +
         (a >> 24) * (b >> 24);
#endif
}

__device__ __forceinline__ float wave_reduce_sum(float v) {
#pragma unroll
  for (int off = 32; off > 0; off >>= 1)
    v += __shfl_xor(v, off, 64);
  return v;
}

__device__ __forceinline__ float wave_reduce_max(float v) {
#pragma unroll
  for (int off = 32; off > 0; off >>= 1)
    v = fmaxf(v, __shfl_xor(v, off, 64));
  return v;
}

__device__ __forceinline__ float dot4(float4 a, float4 b) {
  return a.x * b.x + a.y * b.y + a.z * b.z + a.w * b.w;
}

__device__ __forceinline__ int clampq(float q) {
  int i = (int)rintf(q);
  return i < -127 ? -127 : (i > 127 ? 127 : i);
}

// split fp32 into bf16 hi (truncate) + bf16 lo (exact residual, truncate)
// |x - (hi+lo)| <= 2^-16 |x|  (residual x-hi is exactly representable)
__device__ __forceinline__ void split_bf16(float x, unsigned int& hi,
                                           unsigned int& lo) {
  unsigned int u = __float_as_uint(x);
  hi = u >> 16;
  float hf = __uint_as_float(u & 0xFFFF0000u);
  float r = x - hf;
  lo = __float_as_uint(r) >> 16;
}

// ============ CSR build: 2-level bucket sort, LDS atomics only ============
__global__ __launch_bounds__(256) void hist_coarse(const int* __restrict__ dst,
                                                   int* __restrict__ hist_blk,
                                                   int E, int nbuck) {
  __shared__ int lh[1024];
  int t = threadIdx.x, blk = blockIdx.x;
  for (int i = t; i < nbuck; i += 256) lh[i] = 0;
  __syncthreads();
  int ch = (E + NB_SORT - 1) / NB_SORT;
  int lo = blk * ch, hi = min(E, lo + ch);
  for (int e = lo + t; e < hi; e += 256) atomicAdd(&lh[dst[e] >> 6], 1);
  __syncthreads();
  for (int i = t; i < nbuck; i += 256) hist_blk[i * NB_SORT + blk] = lh[i];
}

__global__ __launch_bounds__(256) void scan_local(int* __restrict__ hist,
                                                  int* __restrict__ bsum,
                                                  int nb) {
  __shared__ int tsum[256];
  int t = threadIdx.x;
  int base = blockIdx.x * 1024 + t * 4;
  int v0 = 0, v1 = 0, v2 = 0, v3 = 0;
  if (base + 3 < nb) {
    int4 q = *(const int4*)&hist[base];
    v0 = q.x; v1 = q.y; v2 = q.z; v3 = q.w;
  } else {
    if (base + 0 < nb) v0 = hist[base + 0];
    if (base + 1 < nb) v1 = hist[base + 1];
    if (base + 2 < nb) v2 = hist[base + 2];
  }
  tsum[t] = v0 + v1 + v2 + v3;
  __syncthreads();
  for (int off = 1; off < 256; off <<= 1) {
    int u = 0;
    if (t >= off) u = tsum[t - off];
    __syncthreads();
    if (t >= off) tsum[t] += u;
    __syncthreads();
  }
  int excl = (t == 0) ? 0 : tsum[t - 1];
  int e0 = excl, e1 = excl + v0, e2 = e1 + v1, e3 = e2 + v2;
  if (base + 3 < nb) {
    *(int4*)&hist[base] = make_int4(e0, e1, e2, e3);
  } else {
    if (base + 0 < nb) hist[base + 0] = e0;
    if (base + 1 < nb) hist[base + 1] = e1;
    if (base + 2 < nb) hist[base + 2] = e2;
  }
  if (t == 255) bsum[blockIdx.x] = tsum[255];
}

__global__ __launch_bounds__(256) void scan_bsum(int* __restrict__ bsum,
                                                 int nblk) {
  __shared__ int sh[256];
  int t = threadIdx.x;
  sh[t] = (t < nblk) ? bsum[t] : 0;
  __syncthreads();
  for (int off = 1; off < 256; off <<= 1) {
    int u = 0;
    if (t >= off) u = sh[t - off];
    __syncthreads();
    if (t >= off) sh[t] += u;
    __syncthreads();
  }
  if (t < nblk) bsum[t] = (t == 0) ? 0 : sh[t - 1];
}

__global__ __launch_bounds__(256) void add_bsum(int* __restrict__ hist,
                                                const int* __restrict__ bsum,
                                                int nb) {
  int i = blockIdx.x * blockDim.x + threadIdx.x;
  if (i < nb) hist[i] += bsum[i >> 10];
}

__global__ __launch_bounds__(256) void scatter_coarse(
    const int* __restrict__ src, const int* __restrict__ dst,
    const int* __restrict__ S, int2* __restrict__ epair, int E, int nbuck) {
  __shared__ int lb[1024];
  int t = threadIdx.x, blk = blockIdx.x;
  for (int i = t; i < nbuck; i += 256) lb[i] = S[i * NB_SORT + blk];
  __syncthreads();
  int ch = (E + NB_SORT - 1) / NB_SORT;
  int lo = blk * ch, hi = min(E, lo + ch);
  for (int e = lo + t; e < hi; e += 256) {
    int d = dst[e];
    int pos = atomicAdd(&lb[d >> 6], 1);
    epair[pos] = make_int2(src[e], d);
  }
}

// emits fully dst-sorted (src,dst) pairs
__global__ __launch_bounds__(256) void fine_sort(
    const int2* __restrict__ epair, const int* __restrict__ S,
    int2* __restrict__ spair, int E, int nbuck) {
  __shared__ int fh[64];
  __shared__ int cur[64];
  int b = blockIdx.x, t = threadIdx.x;
  int bstart = S[b * NB_SORT];
  int bend = (b + 1 < nbuck) ? S[(b + 1) * NB_SORT] : E;
  if (t < 64) fh[t] = 0;
  __syncthreads();
  for (int e = bstart + t; e < bend; e += 256)
    atomicAdd(&fh[epair[e].y & 63], 1);
  __syncthreads();
  if (t < 64) {
    int v = fh[t];
    int incl = v;
#pragma unroll
    for (int off = 1; off < 64; off <<= 1) {
      int u = __shfl_up(incl, off, 64);
      if (t >= off) incl += u;
    }
    cur[t] = incl - v;
  }
  __syncthreads();
  for (int e = bstart + t; e < bend; e += 256) {
    int2 p = epair[e];
    int pos = atomicAdd(&cur[p.y & 63], 1);
    spair[bstart + pos] = p;
  }
}

// ============ prep: quantize + node props + self-loop agg init ============
__global__ __launch_bounds__(256) void prep_x(const float* __restrict__ x,
                                              signed char* __restrict__ qx,
                                              float4* __restrict__ nprop,
                                              float* __restrict__ agg,
                                              int N) {
  int node = (int)((blockIdx.x * blockDim.x + threadIdx.x) >> 6);
  int lane = threadIdx.x & 63;
  if (node >= N) return;
  float2 v = *(const float2*)(x + (size_t)node * 128 + lane * 2);
  float ax = fabsf(v.x), ay = fabsf(v.y);
  float mx = wave_reduce_max(fmaxf(ax, ay));
  float l1 = wave_reduce_sum(ax + ay);
  float ss = wave_reduce_sum(v.x * v.x + v.y * v.y);
  float s = mx * (1.0f / 127.0f);
  float inv = (mx > 0.f) ? 127.0f / mx : 0.f;
  int q0 = clampq(v.x * inv), q1 = clampq(v.y * inv);
  unsigned short w = (unsigned short)((q0 & 0xff) | ((q1 & 0xff) << 8));
  ((unsigned short*)(qx + (size_t)node * 128))[lane] = w;
  float l1q = s * wave_reduce_sum((float)(abs(q0) + abs(q1)));
  bool sp = ss > 0.5f * fmaxf(ss, EPS);
  *(float2*)(agg + (size_t)node * 128 + lane * 2) =
      sp ? v : make_float2(0.f, 0.f);
  if (lane == 0)
    nprop[node] = make_float4(sqrtf(ss), s, fmaxf(l1, l1q), 0.f);
}

__global__ __launch_bounds__(256) void prep_h(const float* __restrict__ h,
                                              signed char* __restrict__ qh,
                                              float4* __restrict__ nprop,
                                              float* __restrict__ agg,
                                              int N) {
  int node = (int)((blockIdx.x * blockDim.x + threadIdx.x) >> 6);
  int lane = threadIdx.x & 63;
  if (node >= N) return;
  float4 v = *(const float4*)(h + (size_t)node * 256 + lane * 4);
  float ax = fabsf(v.x), ay = fabsf(v.y), az = fabsf(v.z), aw = fabsf(v.w);
  float mx = wave_reduce_max(fmaxf(fmaxf(ax, ay), fmaxf(az, aw)));
  float l1 = wave_reduce_sum(ax + ay + az + aw);
  float ss = wave_reduce_sum(dot4(v, v));
  float s = mx * (1.0f / 127.0f);
  float inv = (mx > 0.f) ? 127.0f / mx : 0.f;
  int q0 = clampq(v.x * inv), q1 = clampq(v.y * inv);
  int q2 = clampq(v.z * inv), q3 = clampq(v.w * inv);
  int w = (q0 & 0xff) | ((q1 & 0xff) << 8) | ((q2 & 0xff) << 16) | (q3 << 24);
  ((int*)(qh + (size_t)node * 256))[lane] = w;
  float l1q = s * wave_reduce_sum((float)(abs(q0) + abs(q1) + abs(q2) + abs(q3)));
  bool sp = ss > 0.5f * fmaxf(ss, EPS);
  *(float4*)(agg + (size_t)node * 256 + lane * 4) =
      sp ? v : make_float4(0.f, 0.f, 0.f, 0.f);
  if (lane == 0)
    nprop[node] = make_float4(sqrtf(ss), s, fmaxf(l1, l1q), 0.f);
}

// ====== conv, flat edge-parallel: one thread per edge, no LDS ======
// Edges are fully dst-sorted (spair), so a wave's dst-row reads are
// near-broadcast and L1-hit; source rows are the irreducible random reads.
// Exact path is wave-cooperative via ballot + shuffle (unchanged math).
template <int D>
__global__ __launch_bounds__(256) void conv_flat(
    const float* __restrict__ xf, const signed char* __restrict__ qt,
    const float4* __restrict__ nprop, const int2* __restrict__ spair,
    float* __restrict__ agg, int E) {
  constexpr int NG = D / 16;  // int4 chunks per row
  constexpr int V = D / 64;   // fp32 elems per lane (exact path)
  const int e0 = blockIdx.x * 256 + threadIdx.x;
  const int lane = threadIdx.x & 63;
  const bool valid = e0 < E;
  int2 p = valid ? spair[e0] : make_int2(0, 0);
  const int s = p.x, d = p.y;
  float4 nps = nprop[s];
  float4 npd = nprop[d];
  const signed char* srow = qt + (size_t)s * D;
  const signed char* drow = qt + (size_t)d * D;
  int id = 0;
#pragma unroll
  for (int g = 0; g < NG; ++g) {
    int4 a = *(const int4*)(srow + g * 16);
    int4 bq = *(const int4*)(drow + g * 16);
    id = sdot4i(a.x, bq.x, id);
    id = sdot4i(a.y, bq.y, id);
    id = sdot4i(a.z, bq.z, id);
    id = sdot4i(a.w, bq.w, id);
  }
  float denom = fmaxf(nps.x * npd.x, EPS);
  float thr = 0.5f * denom;
  float approx = (nps.y * npd.y) * (float)id;
  float m = 0.5002f * (nps.y * npd.z + npd.y * nps.z) + 2e-6f * denom + 1e-7f;
  bool maybe = valid && (approx > thr - m);
  unsigned long long mask = __ballot(maybe);
  while (mask) {
    int ln = __ffsll((long long)mask) - 1;
    mask &= mask - 1;
    int es = __shfl(s, ln);
    int ed = __shfl(d, ln);
    float nsx = __shfl(nps.x, ln);
    float ndx = __shfl(npd.x, ln);
    float sv[V], dvv[V];
    if constexpr (V == 2) {
      float2 a = *(const float2*)(xf + (size_t)es * D + lane * 2);
      float2 b = *(const float2*)(xf + (size_t)ed * D + lane * 2);
      sv[0] = a.x; sv[1] = a.y; dvv[0] = b.x; dvv[1] = b.y;
    } else {
      float4 a = *(const float4*)(xf + (size_t)es * D + lane * 4);
      float4 b = *(const float4*)(xf + (size_t)ed * D + lane * 4);
      sv[0] = a.x; sv[1] = a.y; sv[2] = a.z; sv[3] = a.w;
      dvv[0] = b.x; dvv[1] = b.y; dvv[2] = b.z; dvv[3] = b.w;
    }
    float dx = 0.f;
#pragma unroll
    for (int q = 0; q < V; ++q) dx += sv[q] * dvv[q];
    dx = wave_reduce_sum(dx);
    if (dx > 0.5f * fmaxf(nsx * ndx, EPS)) {
      float* arow = agg + (size_t)ed * D + lane * V;
#pragma unroll
      for (int q = 0; q < V; ++q) atomicAdd(&arow[q], sv[q]);
    }
  }
}

// ---------------- GEMM1 via MFMA: h = relu(A @ W^T + b) -------------------
// A[Mx128] fp32 split into bf16 hi+lo (exact residual); 3-term product
// A_hi*W_hi + A_hi*W_lo + A_lo*W_hi gives ~2^-16 relative error (fp32-class).
// BM=128, BN=128, BK=32, 4 waves in 2x2, each wave 64x64 (16 acc tiles).
__global__ __launch_bounds__(256) void gemm1_mfma(
    const float* __restrict__ A, const float* __restrict__ W,
    const float* __restrict__ bias, float* __restrict__ C, int M) {
  constexpr int K = 128, NN = 256, BM = 128, BK = 32, PK = 40;
  __shared__ unsigned short Ah[BM * PK];
  __shared__ unsigned short Al[BM * PK];
  __shared__ unsigned short Wh[BM * PK];
  __shared__ unsigned short Wl[BM * PK];
  const int tid = threadIdx.x;
  const int m0 = blockIdx.x * BM;
  const int n0 = blockIdx.y * BM;
  const int lane = tid & 63;
  const int wv = tid >> 6;
  const int wr = wv >> 1, wc = wv & 1;  // 2x2 wave grid, 64x64 each
  const int lrow = lane & 15, kg = lane >> 4;
  f32x4 acc[4][4] = {};

  for (int k0 = 0; k0 < K; k0 += BK) {
    // ---- stage: global fp32 -> split bf16 hi/lo planes in LDS ----
#pragma unroll
    for (int i = 0; i < 4; ++i) {
      int f = tid + i * 256;
      int r = f >> 3, q = f & 7;  // row 0..127, float4 index 0..7
      int gm = m0 + r;
      float4 a = (gm < M) ? *(const float4*)&A[(size_t)gm * K + k0 + q * 4]
                          : make_float4(0.f, 0.f, 0.f, 0.f);
      float4 w = *(const float4*)&W[(size_t)(n0 + r) * K + k0 + q * 4];
      unsigned int h0, h1, h2, h3, l0, l1, l2, l3;
      split_bf16(a.x, h0, l0); split_bf16(a.y, h1, l1);
      split_bf16(a.z, h2, l2); split_bf16(a.w, h3, l3);
      *(uint2*)&Ah[r * PK + q * 4] =
          make_uint2(h0 | (h1 << 16), h2 | (h3 << 16));
      *(uint2*)&Al[r * PK + q * 4] =
          make_uint2(l0 | (l1 << 16), l2 | (l3 << 16));
      split_bf16(w.x, h0, l0); split_bf16(w.y, h1, l1);
      split_bf16(w.z, h2, l2); split_bf16(w.w, h3, l3);
      *(uint2*)&Wh[r * PK + q * 4] =
          make_uint2(h0 | (h1 << 16), h2 | (h3 << 16));
      *(uint2*)&Wl[r * PK + q * 4] =
          make_uint2(l0 | (l1 << 16), l2 | (l3 << 16));
    }
    __syncthreads();
    // ---- fragments: A row = lane&15, k = (lane>>4)*8 + j ----
    bf16x8 ah[4], al[4], bh[4], bl[4];
#pragma unroll
    for (int m = 0; m < 4; ++m) {
      int row = wr * 64 + m * 16 + lrow;
      ah[m] = *(const bf16x8*)&Ah[row * PK + kg * 8];
      al[m] = *(const bf16x8*)&Al[row * PK + kg * 8];
    }
#pragma unroll
    for (int n = 0; n < 4; ++n) {
      int row = wc * 64 + n * 16 + lrow;
      bh[n] = *(const bf16x8*)&Wh[row * PK + kg * 8];
      bl[n] = *(const bf16x8*)&Wl[row * PK + kg * 8];
    }
#pragma unroll
    for (int m = 0; m < 4; ++m)
#pragma unroll
      for (int n = 0; n < 4; ++n) {
        acc[m][n] = __builtin_amdgcn_mfma_f32_16x16x32_bf16(ah[m], bh[n],
                                                            acc[m][n], 0, 0, 0);
        acc[m][n] = __builtin_amdgcn_mfma_f32_16x16x32_bf16(ah[m], bl[n],
                                                            acc[m][n], 0, 0, 0);
        acc[m][n] = __builtin_amdgcn_mfma_f32_16x16x32_bf16(al[m], bh[n],
                                                            acc[m][n], 0, 0, 0);
      }
    __syncthreads();
  }

  // ---- epilogue: C/D col = lane&15, row = (lane>>4)*4 + reg ----
#pragma unroll
  for (int n = 0; n < 4; ++n) {
    int gc = n0 + wc * 64 + n * 16 + lrow;
    float bv = bias[gc];
#pragma unroll
    for (int m = 0; m < 4; ++m) {
      int gr0 = m0 + wr * 64 + m * 16 + kg * 4;
#pragma unroll
      for (int r = 0; r < 4; ++r) {
        int gm = gr0 + r;
        if (gm < M) {
          float v = acc[m][n][r] + bv;
          C[(size_t)gm * NN + gc] = fmaxf(v, 0.f);
        }
      }
    }
  }
}

// ---- pre-split W2 (64x256 fp32) into bf16 hi/lo planes in workspace ----
__global__ __launch_bounds__(256) void split_w2(
    const float* __restrict__ W, unsigned short* __restrict__ Wh,
    unsigned short* __restrict__ Wl, int total4) {
  int i = blockIdx.x * 256 + threadIdx.x;
  if (i >= total4) return;
  float4 w = ((const float4*)W)[i];
  unsigned int h0, h1, h2, h3, l0, l1, l2, l3;
  split_bf16(w.x, h0, l0); split_bf16(w.y, h1, l1);
  split_bf16(w.z, h2, l2); split_bf16(w.w, h3, l3);
  ((uint2*)Wh)[i] = make_uint2(h0 | (h1 << 16), h2 | (h3 << 16));
  ((uint2*)Wl)[i] = make_uint2(l0 | (l1 << 16), l2 | (l3 << 16));
}

// ------ GEMM2 via MFMA, LDS-free, fused log_softmax: out[Mx64] ------------
__global__ __launch_bounds__(256) void gemm2_mfma_lsm(
    const float* __restrict__ A, const unsigned short* __restrict__ Wh,
    const unsigned short* __restrict__ Wl, const float* __restrict__ bias,
    float* __restrict__ out, int M) {
  constexpr int K = 256;
  const int tid = threadIdx.x;
  const int lane = tid & 63;
  const int wv = tid >> 6;
  const int lrow = lane & 15, kg = lane >> 4;
  const int r0 = blockIdx.x * 128 + wv * 32;  // wave's first row
  f32x4 acc[2][4] = {};

  for (int k0 = 0; k0 < K; k0 += 32) {
    bf16x8 ah[2], al[2];
#pragma unroll
    for (int m = 0; m < 2; ++m) {
      int row = r0 + m * 16 + lrow;  // rows up to 50047 stay inside ws (h)
      const float* ap = A + (size_t)row * K + k0 + kg * 8;
      float4 a0 = *(const float4*)ap;
      float4 a1 = *(const float4*)(ap + 4);
      unsigned int hh[8], ll[8];
      split_bf16(a0.x, hh[0], ll[0]); split_bf16(a0.y, hh[1], ll[1]);
      split_bf16(a0.z, hh[2], ll[2]); split_bf16(a0.w, hh[3], ll[3]);
      split_bf16(a1.x, hh[4], ll[4]); split_bf16(a1.y, hh[5], ll[5]);
      split_bf16(a1.z, hh[6], ll[6]); split_bf16(a1.w, hh[7], ll[7]);
      bf16x8 th, tl;
#pragma unroll
      for (int j = 0; j < 8; ++j) {
        th[j] = (short)hh[j];
        tl[j] = (short)ll[j];
      }
      ah[m] = th;
      al[m] = tl;
    }
    bf16x8 bh[4], bl[4];
#pragma unroll
    for (int n = 0; n < 4; ++n) {
      int wrow = n * 16 + lrow;
      bh[n] = *(const bf16x8*)&Wh[(size_t)wrow * K + k0 + kg * 8];
      bl[n] = *(const bf16x8*)&Wl[(size_t)wrow * K + k0 + kg * 8];
    }
#pragma unroll
    for (int m = 0; m < 2; ++m)
#pragma unroll
      for (int n = 0; n < 4; ++n) {
        acc[m][n] = __builtin_amdgcn_mfma_f32_16x16x32_bf16(ah[m], bh[n],
                                                            acc[m][n], 0, 0, 0);
        acc[m][n] = __builtin_amdgcn_mfma_f32_16x16x32_bf16(ah[m], bl[n],
                                                            acc[m][n], 0, 0, 0);
        acc[m][n] = __builtin_amdgcn_mfma_f32_16x16x32_bf16(al[m], bh[n],
                                                            acc[m][n], 0, 0, 0);
      }
  }

  float bv[4];
#pragma unroll
  for (int n = 0; n < 4; ++n) bv[n] = bias[n * 16 + lrow];
#pragma unroll
  for (int m = 0; m < 2; ++m)
#pragma unroll
    for (int r = 0; r < 4; ++r) {
      int row = r0 + m * 16 + kg * 4 + r;
      float v[4];
      float mx = -1e30f;
#pragma unroll
      for (int n = 0; n < 4; ++n) {
        v[n] = acc[m][n][r] + bv[n];
        mx = fmaxf(mx, v[n]);
      }
#pragma unroll
      for (int off = 8; off > 0; off >>= 1)
        mx = fmaxf(mx, __shfl_xor(mx, off, 64));
      float s = 0.f;
#pragma unroll
      for (int n = 0; n < 4; ++n) s += expf(v[n] - mx);
#pragma unroll
      for (int off = 8; off > 0; off >>= 1) s += __shfl_xor(s, off, 64);
      float lg = logf(s);
      if (row < M) {
#pragma unroll
        for (int n = 0; n < 4; ++n)
          out[(size_t)row * 64 + n * 16 + lrow] = v[n] - mx - lg;
      }
    }
}

extern "C" void kernel_launch(void* const* d_in, const int* in_sizes, int n_in,
                              void* d_out, int out_size, void* d_ws,
                              size_t ws_size, hipStream_t stream) {
  const float* x  = (const float*)d_in[0];
  const int* eidx = (const int*)d_in[1];
  const float* W1 = (const float*)d_in[2];
  const float* b1 = (const float*)d_in[3];
  const float* W2 = (const float*)d_in[4];
  const float* b2 = (const float*)d_in[5];
  float* out = (float*)d_out;

  const int N = in_sizes[0] / 128;  // 50000
  const int E = in_sizes[1] / 2;    // 800000
  const int* src = eidx;
  const int* dst = eidx + E;

  const int nbuck = (N + 63) / 64;         // 782
  const int ntot = nbuck * NB_SORT;        // 200192
  const int nblk2 = (ntot + 1023) / 1024;  // 196

  float* agg    = (float*)d_ws;
  float* h      = agg + (size_t)N * 256;
  float4* npx   = (float4*)(h + (size_t)N * 256);
  float4* nph   = npx + N;
  int* S        = (int*)(nph + N);
  int* bsum     = S + ntot;
  int2* spair   = (int2*)(bsum + 256);
  signed char* qh = (signed char*)(spair + E);
  unsigned short* W2h = (unsigned short*)(qh + (size_t)N * 256);
  unsigned short* W2l = W2h + 64 * 256;
  int2* epair   = (int2*)h;                              // overlap (6.4 MB)
  signed char* qx = (signed char*)(h + (size_t)N * 64);  // overlap (6.4 MB)

  // ---- pre-split W2 into bf16 hi/lo planes (L2-resident afterwards) ----
  split_w2<<<16, 256, 0, stream>>>(W2, W2h, W2l, 64 * 256 / 4);

  // ---- build dst-sorted edge list with LDS-only atomics ----
  hist_coarse<<<NB_SORT, 256, 0, stream>>>(dst, S, E, nbuck);
  scan_local<<<nblk2, 256, 0, stream>>>(S, bsum, ntot);
  scan_bsum<<<1, 256, 0, stream>>>(bsum, nblk2);
  add_bsum<<<(ntot + 255) / 256, 256, 0, stream>>>(S, bsum, ntot);
  scatter_coarse<<<NB_SORT, 256, 0, stream>>>(src, dst, S, epair, E, nbuck);
  fine_sort<<<nbuck, 256, 0, stream>>>(epair, S, spair, E, nbuck);

  const int nblkE = (E + 255) / 256;

  // ---- layer 1 (D=128) ----
  prep_x<<<(N + 3) / 4, 256, 0, stream>>>(x, qx, npx, agg, N);
  conv_flat<128><<<nblkE, 256, 0, stream>>>(x, qx, npx, spair, agg, E);
  gemm1_mfma<<<dim3((N + 127) / 128, 2), 256, 0, stream>>>(agg, W1, b1, h, N);

  // ---- layer 2 (D=256) ----
  prep_h<<<(N + 3) / 4, 256, 0, stream>>>(h, qh, nph, agg, N);
  conv_flat<256><<<nblkE, 256, 0, stream>>>(h, qh, nph, spair, agg, E);
  gemm2_mfma_lsm<<<dim3((N + 127) / 128), 256, 0, stream>>>(agg, W2h, W2l, b2,
                                                            out, N);
}

// Round 4
// 275.509 us; speedup vs baseline: 1.1970x; 1.0749x over previous
//
#include <hip/hip_runtime.h>
#include <math.h>

#define EPS 1e-8f
#define NB_SORT 256  // blocks in coarse sort phases

#if defined(__has_builtin)
#if __has_builtin(__builtin_amdgcn_sdot4)
#define HAVE_SDOT4 1
#endif
#endif

typedef __attribute__((ext_vector_type(8))) short bf16x8;
typedef __attribute__((ext_vector_type(4))) float f32x4;

__device__ __forceinline__ int sdot4i(int a, int b, int c) {
#ifdef HAVE_SDOT4
  return __builtin_amdgcn_sdot4(a, b, c, false);
#else
  return c + ((int)(signed char)(a)) * ((int)(signed char)(b)) +
         ((int)(signed char)(a >> 8)) * ((int)(signed char)(b >> 8)) +
         ((int)(signed char)(a >> 16)) * ((int)(signed char)(b >> 16)) +
         (a >> 24) * (b >> 24);
#endif
}

__device__ __forceinline__ float wave_reduce_sum(float v) {
#pragma unroll
  for (int off = 32; off > 0; off >>= 1)
    v += __shfl_xor(v, off, 64);
  return v;
}

__device__ __forceinline__ float wave_reduce_max(float v) {
#pragma unroll
  for (int off = 32; off > 0; off >>= 1)
    v = fmaxf(v, __shfl_xor(v, off, 64));
  return v;
}

__device__ __forceinline__ float dot4(float4 a, float4 b) {
  return a.x * b.x + a.y * b.y + a.z * b.z + a.w * b.w;
}

__device__ __forceinline__ int clampq(float q) {
  int i = (int)rintf(q);
  return i < -127 ? -127 : (i > 127 ? 127 : i);
}

// split fp32 into bf16 hi (truncate) + bf16 lo (exact residual, truncate)
// |x - (hi+lo)| <= 2^-16 |x|  (residual x-hi is exactly representable)
__device__ __forceinline__ void split_bf16(float x, unsigned int& hi,
                                           unsigned int& lo) {
  unsigned int u = __float_as_uint(x);
  hi = u >> 16;
  float hf = __uint_as_float(u & 0xFFFF0000u);
  float r = x - hf;
  lo = __float_as_uint(r) >> 16;
}

// ============ CSR build: 2-level bucket sort, LDS atomics only ============
__global__ __launch_bounds__(256) void hist_coarse(const int* __restrict__ dst,
                                                   int* __restrict__ hist_blk,
                                                   int E, int nbuck) {
  __shared__ int lh[1024];
  int t = threadIdx.x, blk = blockIdx.x;
  for (int i = t; i < nbuck; i += 256) lh[i] = 0;
  __syncthreads();
  int ch = (E + NB_SORT - 1) / NB_SORT;
  int lo = blk * ch, hi = min(E, lo + ch);
  for (int e = lo + t; e < hi; e += 256) atomicAdd(&lh[dst[e] >> 6], 1);
  __syncthreads();
  for (int i = t; i < nbuck; i += 256) hist_blk[i * NB_SORT + blk] = lh[i];
}

__global__ __launch_bounds__(256) void scan_local(int* __restrict__ hist,
                                                  int* __restrict__ bsum,
                                                  int nb) {
  __shared__ int tsum[256];
  int t = threadIdx.x;
  int base = blockIdx.x * 1024 + t * 4;
  int v0 = 0, v1 = 0, v2 = 0, v3 = 0;
  if (base + 3 < nb) {
    int4 q = *(const int4*)&hist[base];
    v0 = q.x; v1 = q.y; v2 = q.z; v3 = q.w;
  } else {
    if (base + 0 < nb) v0 = hist[base + 0];
    if (base + 1 < nb) v1 = hist[base + 1];
    if (base + 2 < nb) v2 = hist[base + 2];
  }
  tsum[t] = v0 + v1 + v2 + v3;
  __syncthreads();
  for (int off = 1; off < 256; off <<= 1) {
    int u = 0;
    if (t >= off) u = tsum[t - off];
    __syncthreads();
    if (t >= off) tsum[t] += u;
    __syncthreads();
  }
  int excl = (t == 0) ? 0 : tsum[t - 1];
  int e0 = excl, e1 = excl + v0, e2 = e1 + v1, e3 = e2 + v2;
  if (base + 3 < nb) {
    *(int4*)&hist[base] = make_int4(e0, e1, e2, e3);
  } else {
    if (base + 0 < nb) hist[base + 0] = e0;
    if (base + 1 < nb) hist[base + 1] = e1;
    if (base + 2 < nb) hist[base + 2] = e2;
  }
  if (t == 255) bsum[blockIdx.x] = tsum[255];
}

__global__ __launch_bounds__(256) void scan_bsum(int* __restrict__ bsum,
                                                 int nblk) {
  __shared__ int sh[256];
  int t = threadIdx.x;
  sh[t] = (t < nblk) ? bsum[t] : 0;
  __syncthreads();
  for (int off = 1; off < 256; off <<= 1) {
    int u = 0;
    if (t >= off) u = sh[t - off];
    __syncthreads();
    if (t >= off) sh[t] += u;
    __syncthreads();
  }
  if (t < nblk) bsum[t] = (t == 0) ? 0 : sh[t - 1];
}

__global__ __launch_bounds__(256) void add_bsum(int* __restrict__ hist,
                                                const int* __restrict__ bsum,
                                                int nb) {
  int i = blockIdx.x * blockDim.x + threadIdx.x;
  if (i < nb) hist[i] += bsum[i >> 10];
}

__global__ __launch_bounds__(256) void scatter_coarse(
    const int* __restrict__ src, const int* __restrict__ dst,
    const int* __restrict__ S, int2* __restrict__ epair, int E, int nbuck) {
  __shared__ int lb[1024];
  int t = threadIdx.x, blk = blockIdx.x;
  for (int i = t; i < nbuck; i += 256) lb[i] = S[i * NB_SORT + blk];
  __syncthreads();
  int ch = (E + NB_SORT - 1) / NB_SORT;
  int lo = blk * ch, hi = min(E, lo + ch);
  for (int e = lo + t; e < hi; e += 256) {
    int d = dst[e];
    int pos = atomicAdd(&lb[d >> 6], 1);
    epair[pos] = make_int2(src[e], d);
  }
}

// emits fully dst-sorted (src,dst) pairs
__global__ __launch_bounds__(256) void fine_sort(
    const int2* __restrict__ epair, const int* __restrict__ S,
    int2* __restrict__ spair, int E, int nbuck) {
  __shared__ int fh[64];
  __shared__ int cur[64];
  int b = blockIdx.x, t = threadIdx.x;
  int bstart = S[b * NB_SORT];
  int bend = (b + 1 < nbuck) ? S[(b + 1) * NB_SORT] : E;
  if (t < 64) fh[t] = 0;
  __syncthreads();
  for (int e = bstart + t; e < bend; e += 256)
    atomicAdd(&fh[epair[e].y & 63], 1);
  __syncthreads();
  if (t < 64) {
    int v = fh[t];
    int incl = v;
#pragma unroll
    for (int off = 1; off < 64; off <<= 1) {
      int u = __shfl_up(incl, off, 64);
      if (t >= off) incl += u;
    }
    cur[t] = incl - v;
  }
  __syncthreads();
  for (int e = bstart + t; e < bend; e += 256) {
    int2 p = epair[e];
    int pos = atomicAdd(&cur[p.y & 63], 1);
    spair[bstart + pos] = p;
  }
}

// ============ prep: quantize + node props + self-loop agg init ============
__global__ __launch_bounds__(256) void prep_x(const float* __restrict__ x,
                                              signed char* __restrict__ qx,
                                              float4* __restrict__ nprop,
                                              float* __restrict__ agg,
                                              int N) {
  int node = (int)((blockIdx.x * blockDim.x + threadIdx.x) >> 6);
  int lane = threadIdx.x & 63;
  if (node >= N) return;
  float2 v = *(const float2*)(x + (size_t)node * 128 + lane * 2);
  float ax = fabsf(v.x), ay = fabsf(v.y);
  float mx = wave_reduce_max(fmaxf(ax, ay));
  float l1 = wave_reduce_sum(ax + ay);
  float ss = wave_reduce_sum(v.x * v.x + v.y * v.y);
  float s = mx * (1.0f / 127.0f);
  float inv = (mx > 0.f) ? 127.0f / mx : 0.f;
  int q0 = clampq(v.x * inv), q1 = clampq(v.y * inv);
  unsigned short w = (unsigned short)((q0 & 0xff) | ((q1 & 0xff) << 8));
  ((unsigned short*)(qx + (size_t)node * 128))[lane] = w;
  float l1q = s * wave_reduce_sum((float)(abs(q0) + abs(q1)));
  bool sp = ss > 0.5f * fmaxf(ss, EPS);
  *(float2*)(agg + (size_t)node * 128 + lane * 2) =
      sp ? v : make_float2(0.f, 0.f);
  if (lane == 0)
    nprop[node] = make_float4(sqrtf(ss), s, fmaxf(l1, l1q), 0.f);
}

__global__ __launch_bounds__(256) void prep_h(const float* __restrict__ h,
                                              signed char* __restrict__ qh,
                                              float4* __restrict__ nprop,
                                              float* __restrict__ agg,
                                              int N) {
  int node = (int)((blockIdx.x * blockDim.x + threadIdx.x) >> 6);
  int lane = threadIdx.x & 63;
  if (node >= N) return;
  float4 v = *(const float4*)(h + (size_t)node * 256 + lane * 4);
  float ax = fabsf(v.x), ay = fabsf(v.y), az = fabsf(v.z), aw = fabsf(v.w);
  float mx = wave_reduce_max(fmaxf(fmaxf(ax, ay), fmaxf(az, aw)));
  float l1 = wave_reduce_sum(ax + ay + az + aw);
  float ss = wave_reduce_sum(dot4(v, v));
  float s = mx * (1.0f / 127.0f);
  float inv = (mx > 0.f) ? 127.0f / mx : 0.f;
  int q0 = clampq(v.x * inv), q1 = clampq(v.y * inv);
  int q2 = clampq(v.z * inv), q3 = clampq(v.w * inv);
  int w = (q0 & 0xff) | ((q1 & 0xff) << 8) | ((q2 & 0xff) << 16) | (q3 << 24);
  ((int*)(qh + (size_t)node * 256))[lane] = w;
  float l1q = s * wave_reduce_sum((float)(abs(q0) + abs(q1) + abs(q2) + abs(q3)));
  bool sp = ss > 0.5f * fmaxf(ss, EPS);
  *(float4*)(agg + (size_t)node * 256 + lane * 4) =
      sp ? v : make_float4(0.f, 0.f, 0.f, 0.f);
  if (lane == 0)
    nprop[node] = make_float4(sqrtf(ss), s, fmaxf(l1, l1q), 0.f);
}

// ====== conv, group-cooperative: G = D/16 lanes per edge ======
// Each G-lane group reads its edge's src/dst int8 rows COALESCED (one int4
// per lane covers the row), computes the quantized dot via sdot4 + in-group
// shfl_xor reduce. Margin test then splits edges into:
//   defpass: approx - m > thr  -> true dot certainly passes; add row, no check
//   amb:     |approx - thr| <= m -> full-wave exact fp32 recompute (as before)
// Edges are dst-sorted so dst rows/nprop are L1-broadcast within a wave.
template <int D>
__global__ __launch_bounds__(256) void conv_coop(
    const float* __restrict__ xf, const signed char* __restrict__ qt,
    const float4* __restrict__ nprop, const int2* __restrict__ spair,
    float* __restrict__ agg, int E) {
  constexpr int G = D / 16;    // lanes per edge: 8 (D=128) / 16 (D=256)
  constexpr int EPW = 64 / G;  // edges per wave: 8 / 4
  constexpr int V = D / 64;    // fp32 elems per lane, full-wave path
  const int tid = threadIdx.x;
  const int lane = tid & 63;
  const int wv = tid >> 6;
  const int g = lane & (G - 1);
  const int sub = lane / G;
  const int e = (blockIdx.x * 4 + wv) * EPW + sub;
  const bool valid = e < E;
  int2 p = spair[valid ? e : (E - 1)];
  const int s = p.x, d = p.y;
  float4 nps = nprop[s];
  float4 npd = nprop[d];
  int id = 0;
  {
    int4 a = *(const int4*)(qt + (size_t)s * D + g * 16);
    int4 bq = *(const int4*)(qt + (size_t)d * D + g * 16);
    id = sdot4i(a.x, bq.x, id);
    id = sdot4i(a.y, bq.y, id);
    id = sdot4i(a.z, bq.z, id);
    id = sdot4i(a.w, bq.w, id);
  }
#pragma unroll
  for (int off = G / 2; off > 0; off >>= 1) id += __shfl_xor(id, off, 64);
  float denom = fmaxf(nps.x * npd.x, EPS);
  float thr = 0.5f * denom;
  float approx = (nps.y * npd.y) * (float)id;
  float m = 0.5002f * (nps.y * npd.z + npd.y * nps.z) + 2e-6f * denom + 1e-7f;
  bool maybe = valid && (approx > thr - m);
  bool defp = maybe && (approx - m > thr);  // certainly above threshold
  bool amb = maybe && !defp;                // needs exact recompute
  unsigned long long defmask = __ballot(defp && g == 0);
  unsigned long long ambmask = __ballot(amb && g == 0);
  // ---- definite passes: add xf[src] into agg[dst], no dot needed ----
  while (defmask) {
    int ln = __ffsll((long long)defmask) - 1;
    defmask &= defmask - 1;
    int es = __shfl(s, ln);
    int ed = __shfl(d, ln);
    float* arow = agg + (size_t)ed * D + lane * V;
    if constexpr (V == 2) {
      float2 a = *(const float2*)(xf + (size_t)es * D + lane * 2);
      atomicAdd(&arow[0], a.x);
      atomicAdd(&arow[1], a.y);
    } else {
      float4 a = *(const float4*)(xf + (size_t)es * D + lane * 4);
      atomicAdd(&arow[0], a.x);
      atomicAdd(&arow[1], a.y);
      atomicAdd(&arow[2], a.z);
      atomicAdd(&arow[3], a.w);
    }
  }
  // ---- ambiguous: full-wave exact fp32 check (unchanged math) ----
  while (ambmask) {
    int ln = __ffsll((long long)ambmask) - 1;
    ambmask &= ambmask - 1;
    int es = __shfl(s, ln);
    int ed = __shfl(d, ln);
    float nsx = __shfl(nps.x, ln);
    float ndx = __shfl(npd.x, ln);
    float sv[V], dvv[V];
    if constexpr (V == 2) {
      float2 a = *(const float2*)(xf + (size_t)es * D + lane * 2);
      float2 b = *(const float2*)(xf + (size_t)ed * D + lane * 2);
      sv[0] = a.x; sv[1] = a.y; dvv[0] = b.x; dvv[1] = b.y;
    } else {
      float4 a = *(const float4*)(xf + (size_t)es * D + lane * 4);
      float4 b = *(const float4*)(xf + (size_t)ed * D + lane * 4);
      sv[0] = a.x; sv[1] = a.y; sv[2] = a.z; sv[3] = a.w;
      dvv[0] = b.x; dvv[1] = b.y; dvv[2] = b.z; dvv[3] = b.w;
    }
    float dx = 0.f;
#pragma unroll
    for (int q = 0; q < V; ++q) dx += sv[q] * dvv[q];
    dx = wave_reduce_sum(dx);
    if (dx > 0.5f * fmaxf(nsx * ndx, EPS)) {
      float* arow = agg + (size_t)ed * D + lane * V;
#pragma unroll
      for (int q = 0; q < V; ++q) atomicAdd(&arow[q], sv[q]);
    }
  }
}

// ---------------- GEMM1 via MFMA: h = relu(A @ W^T + b) -------------------
// A[Mx128] fp32 split into bf16 hi+lo (exact residual); 3-term product
// A_hi*W_hi + A_hi*W_lo + A_lo*W_hi gives ~2^-16 relative error (fp32-class).
// BM=128, BN=128, BK=32, 4 waves in 2x2, each wave 64x64 (16 acc tiles).
__global__ __launch_bounds__(256) void gemm1_mfma(
    const float* __restrict__ A, const float* __restrict__ W,
    const float* __restrict__ bias, float* __restrict__ C, int M) {
  constexpr int K = 128, NN = 256, BM = 128, BK = 32, PK = 40;
  __shared__ unsigned short Ah[BM * PK];
  __shared__ unsigned short Al[BM * PK];
  __shared__ unsigned short Wh[BM * PK];
  __shared__ unsigned short Wl[BM * PK];
  const int tid = threadIdx.x;
  const int m0 = blockIdx.x * BM;
  const int n0 = blockIdx.y * BM;
  const int lane = tid & 63;
  const int wv = tid >> 6;
  const int wr = wv >> 1, wc = wv & 1;  // 2x2 wave grid, 64x64 each
  const int lrow = lane & 15, kg = lane >> 4;
  f32x4 acc[4][4] = {};

  for (int k0 = 0; k0 < K; k0 += BK) {
    // ---- stage: global fp32 -> split bf16 hi/lo planes in LDS ----
#pragma unroll
    for (int i = 0; i < 4; ++i) {
      int f = tid + i * 256;
      int r = f >> 3, q = f & 7;  // row 0..127, float4 index 0..7
      int gm = m0 + r;
      float4 a = (gm < M) ? *(const float4*)&A[(size_t)gm * K + k0 + q * 4]
                          : make_float4(0.f, 0.f, 0.f, 0.f);
      float4 w = *(const float4*)&W[(size_t)(n0 + r) * K + k0 + q * 4];
      unsigned int h0, h1, h2, h3, l0, l1, l2, l3;
      split_bf16(a.x, h0, l0); split_bf16(a.y, h1, l1);
      split_bf16(a.z, h2, l2); split_bf16(a.w, h3, l3);
      *(uint2*)&Ah[r * PK + q * 4] =
          make_uint2(h0 | (h1 << 16), h2 | (h3 << 16));
      *(uint2*)&Al[r * PK + q * 4] =
          make_uint2(l0 | (l1 << 16), l2 | (l3 << 16));
      split_bf16(w.x, h0, l0); split_bf16(w.y, h1, l1);
      split_bf16(w.z, h2, l2); split_bf16(w.w, h3, l3);
      *(uint2*)&Wh[r * PK + q * 4] =
          make_uint2(h0 | (h1 << 16), h2 | (h3 << 16));
      *(uint2*)&Wl[r * PK + q * 4] =
          make_uint2(l0 | (l1 << 16), l2 | (l3 << 16));
    }
    __syncthreads();
    // ---- fragments: A row = lane&15, k = (lane>>4)*8 + j ----
    bf16x8 ah[4], al[4], bh[4], bl[4];
#pragma unroll
    for (int m = 0; m < 4; ++m) {
      int row = wr * 64 + m * 16 + lrow;
      ah[m] = *(const bf16x8*)&Ah[row * PK + kg * 8];
      al[m] = *(const bf16x8*)&Al[row * PK + kg * 8];
    }
#pragma unroll
    for (int n = 0; n < 4; ++n) {
      int row = wc * 64 + n * 16 + lrow;
      bh[n] = *(const bf16x8*)&Wh[row * PK + kg * 8];
      bl[n] = *(const bf16x8*)&Wl[row * PK + kg * 8];
    }
#pragma unroll
    for (int m = 0; m < 4; ++m)
#pragma unroll
      for (int n = 0; n < 4; ++n) {
        acc[m][n] = __builtin_amdgcn_mfma_f32_16x16x32_bf16(ah[m], bh[n],
                                                            acc[m][n], 0, 0, 0);
        acc[m][n] = __builtin_amdgcn_mfma_f32_16x16x32_bf16(ah[m], bl[n],
                                                            acc[m][n], 0, 0, 0);
        acc[m][n] = __builtin_amdgcn_mfma_f32_16x16x32_bf16(al[m], bh[n],
                                                            acc[m][n], 0, 0, 0);
      }
    __syncthreads();
  }

  // ---- epilogue: C/D col = lane&15, row = (lane>>4)*4 + reg ----
#pragma unroll
  for (int n = 0; n < 4; ++n) {
    int gc = n0 + wc * 64 + n * 16 + lrow;
    float bv = bias[gc];
#pragma unroll
    for (int m = 0; m < 4; ++m) {
      int gr0 = m0 + wr * 64 + m * 16 + kg * 4;
#pragma unroll
      for (int r = 0; r < 4; ++r) {
        int gm = gr0 + r;
        if (gm < M) {
          float v = acc[m][n][r] + bv;
          C[(size_t)gm * NN + gc] = fmaxf(v, 0.f);
        }
      }
    }
  }
}

// ---- pre-split W2 (64x256 fp32) into bf16 hi/lo planes in workspace ----
__global__ __launch_bounds__(256) void split_w2(
    const float* __restrict__ W, unsigned short* __restrict__ Wh,
    unsigned short* __restrict__ Wl, int total4) {
  int i = blockIdx.x * 256 + threadIdx.x;
  if (i >= total4) return;
  float4 w = ((const float4*)W)[i];
  unsigned int h0, h1, h2, h3, l0, l1, l2, l3;
  split_bf16(w.x, h0, l0); split_bf16(w.y, h1, l1);
  split_bf16(w.z, h2, l2); split_bf16(w.w, h3, l3);
  ((uint2*)Wh)[i] = make_uint2(h0 | (h1 << 16), h2 | (h3 << 16));
  ((uint2*)Wl)[i] = make_uint2(l0 | (l1 << 16), l2 | (l3 << 16));
}

// ------ GEMM2 via MFMA, LDS-free, fused log_softmax: out[Mx64] ------------
__global__ __launch_bounds__(256) void gemm2_mfma_lsm(
    const float* __restrict__ A, const unsigned short* __restrict__ Wh,
    const unsigned short* __restrict__ Wl, const float* __restrict__ bias,
    float* __restrict__ out, int M) {
  constexpr int K = 256;
  const int tid = threadIdx.x;
  const int lane = tid & 63;
  const int wv = tid >> 6;
  const int lrow = lane & 15, kg = lane >> 4;
  const int r0 = blockIdx.x * 128 + wv * 32;  // wave's first row
  f32x4 acc[2][4] = {};

  for (int k0 = 0; k0 < K; k0 += 32) {
    bf16x8 ah[2], al[2];
#pragma unroll
    for (int m = 0; m < 2; ++m) {
      int row = r0 + m * 16 + lrow;  // rows up to 50047 stay inside ws (h)
      const float* ap = A + (size_t)row * K + k0 + kg * 8;
      float4 a0 = *(const float4*)ap;
      float4 a1 = *(const float4*)(ap + 4);
      unsigned int hh[8], ll[8];
      split_bf16(a0.x, hh[0], ll[0]); split_bf16(a0.y, hh[1], ll[1]);
      split_bf16(a0.z, hh[2], ll[2]); split_bf16(a0.w, hh[3], ll[3]);
      split_bf16(a1.x, hh[4], ll[4]); split_bf16(a1.y, hh[5], ll[5]);
      split_bf16(a1.z, hh[6], ll[6]); split_bf16(a1.w, hh[7], ll[7]);
      bf16x8 th, tl;
#pragma unroll
      for (int j = 0; j < 8; ++j) {
        th[j] = (short)hh[j];
        tl[j] = (short)ll[j];
      }
      ah[m] = th;
      al[m] = tl;
    }
    bf16x8 bh[4], bl[4];
#pragma unroll
    for (int n = 0; n < 4; ++n) {
      int wrow = n * 16 + lrow;
      bh[n] = *(const bf16x8*)&Wh[(size_t)wrow * K + k0 + kg * 8];
      bl[n] = *(const bf16x8*)&Wl[(size_t)wrow * K + k0 + kg * 8];
    }
#pragma unroll
    for (int m = 0; m < 2; ++m)
#pragma unroll
      for (int n = 0; n < 4; ++n) {
        acc[m][n] = __builtin_amdgcn_mfma_f32_16x16x32_bf16(ah[m], bh[n],
                                                            acc[m][n], 0, 0, 0);
        acc[m][n] = __builtin_amdgcn_mfma_f32_16x16x32_bf16(ah[m], bl[n],
                                                            acc[m][n], 0, 0, 0);
        acc[m][n] = __builtin_amdgcn_mfma_f32_16x16x32_bf16(al[m], bh[n],
                                                            acc[m][n], 0, 0, 0);
      }
  }

  float bv[4];
#pragma unroll
  for (int n = 0; n < 4; ++n) bv[n] = bias[n * 16 + lrow];
#pragma unroll
  for (int m = 0; m < 2; ++m)
#pragma unroll
    for (int r = 0; r < 4; ++r) {
      int row = r0 + m * 16 + kg * 4 + r;
      float v[4];
      float mx = -1e30f;
#pragma unroll
      for (int n = 0; n < 4; ++n) {
        v[n] = acc[m][n][r] + bv[n];
        mx = fmaxf(mx, v[n]);
      }
#pragma unroll
      for (int off = 8; off > 0; off >>= 1)
        mx = fmaxf(mx, __shfl_xor(mx, off, 64));
      float s = 0.f;
#pragma unroll
      for (int n = 0; n < 4; ++n) s += expf(v[n] - mx);
#pragma unroll
      for (int off = 8; off > 0; off >>= 1) s += __shfl_xor(s, off, 64);
      float lg = logf(s);
      if (row < M) {
#pragma unroll
        for (int n = 0; n < 4; ++n)
          out[(size_t)row * 64 + n * 16 + lrow] = v[n] - mx - lg;
      }
    }
}

extern "C" void kernel_launch(void* const* d_in, const int* in_sizes, int n_in,
                              void* d_out, int out_size, void* d_ws,
                              size_t ws_size, hipStream_t stream) {
  const float* x  = (const float*)d_in[0];
  const int* eidx = (const int*)d_in[1];
  const float* W1 = (const float*)d_in[2];
  const float* b1 = (const float*)d_in[3];
  const float* W2 = (const float*)d_in[4];
  const float* b2 = (const float*)d_in[5];
  float* out = (float*)d_out;

  const int N = in_sizes[0] / 128;  // 50000
  const int E = in_sizes[1] / 2;    // 800000
  const int* src = eidx;
  const int* dst = eidx + E;

  const int nbuck = (N + 63) / 64;         // 782
  const int ntot = nbuck * NB_SORT;        // 200192
  const int nblk2 = (ntot + 1023) / 1024;  // 196

  float* agg    = (float*)d_ws;
  float* h      = agg + (size_t)N * 256;
  float4* npx   = (float4*)(h + (size_t)N * 256);
  float4* nph   = npx + N;
  int* S        = (int*)(nph + N);
  int* bsum     = S + ntot;
  int2* spair   = (int2*)(bsum + 256);
  signed char* qh = (signed char*)(spair + E);
  unsigned short* W2h = (unsigned short*)(qh + (size_t)N * 256);
  unsigned short* W2l = W2h + 64 * 256;
  int2* epair   = (int2*)h;                              // overlap (6.4 MB)
  signed char* qx = (signed char*)(h + (size_t)N * 64);  // overlap (6.4 MB)

  // ---- pre-split W2 into bf16 hi/lo planes (L2-resident afterwards) ----
  split_w2<<<16, 256, 0, stream>>>(W2, W2h, W2l, 64 * 256 / 4);

  // ---- build dst-sorted edge list with LDS-only atomics ----
  hist_coarse<<<NB_SORT, 256, 0, stream>>>(dst, S, E, nbuck);
  scan_local<<<nblk2, 256, 0, stream>>>(S, bsum, ntot);
  scan_bsum<<<1, 256, 0, stream>>>(bsum, nblk2);
  add_bsum<<<(ntot + 255) / 256, 256, 0, stream>>>(S, bsum, ntot);
  scatter_coarse<<<NB_SORT, 256, 0, stream>>>(src, dst, S, epair, E, nbuck);
  fine_sort<<<nbuck, 256, 0, stream>>>(epair, S, spair, E, nbuck);

  // ---- layer 1 (D=128): 8 lanes/edge -> 32 edges per 256-thr block ----
  prep_x<<<(N + 3) / 4, 256, 0, stream>>>(x, qx, npx, agg, N);
  conv_coop<128><<<(E + 31) / 32, 256, 0, stream>>>(x, qx, npx, spair, agg, E);
  gemm1_mfma<<<dim3((N + 127) / 128, 2), 256, 0, stream>>>(agg, W1, b1, h, N);

  // ---- layer 2 (D=256): 16 lanes/edge -> 16 edges per 256-thr block ----
  prep_h<<<(N + 3) / 4, 256, 0, stream>>>(h, qh, nph, agg, N);
  conv_coop<256><<<(E + 15) / 16, 256, 0, stream>>>(h, qh, nph, spair, agg, E);
  gemm2_mfma_lsm<<<dim3((N + 127) / 128), 256, 0, stream>>>(agg, W2h, W2l, b2,
                                                            out, N);
}